// Round 3
// baseline (3573.497 us; speedup 1.0000x reference)
//
#include <hip/hip_runtime.h>
#include <hip/hip_bf16.h>
#include <math.h>

#define N_NODES 50000
#define N_EDGES 500000
#define B_GRAPHS 8
#define NPG 6250
#define HID 64
#define HO 128          // HEADS*HID
#define IN_DIM 10
#define F_TOT 266       // IN_DIM + 4*HID
#define OUT_C 532       // 2*F_TOT
#define NEG_SLOPE 0.2f
#define NT_ROWS 44      // 7 etype + 31 rid + 2 rc + 3 rp + 1 const

// dtype-agnostic float load: f32 flag chooses fp32 or bf16 interpretation
__device__ __forceinline__ float LD(const void* p, size_t i, int f32) {
    if (f32) return ((const float*)p)[i];
    unsigned u = ((const unsigned short*)p)[i];
    return __uint_as_float(u << 16);
}
// monotone float<->uint key for atomicMax on floats (memset-0 == -infinity)
__device__ __forceinline__ unsigned fkey(float f) {
    unsigned b = __float_as_uint(f);
    return (b & 0x80000000u) ? ~b : (b | 0x80000000u);
}
__device__ __forceinline__ float funkey(unsigned k) {
    unsigned b = (k & 0x80000000u) ? (k & 0x7fffffffu) : ~k;
    return __uint_as_float(b);
}
__device__ __forceinline__ float fcomp(const float4& v, int k) {
    return k == 0 ? v.x : k == 1 ? v.y : k == 2 ? v.z : v.w;
}
// wave64 sum: 4 DPP steps (VALU pipe) for 16-lane rows, then 2 shfl across rows
__device__ __forceinline__ float wsum(float x) {
    x += __int_as_float(__builtin_amdgcn_update_dpp(0, __float_as_int(x), 0xB1, 0xF, 0xF, true));  // quad xor1
    x += __int_as_float(__builtin_amdgcn_update_dpp(0, __float_as_int(x), 0x4E, 0xF, 0xF, true));  // quad xor2
    x += __int_as_float(__builtin_amdgcn_update_dpp(0, __float_as_int(x), 0x141, 0xF, 0xF, true)); // half-row mirror
    x += __int_as_float(__builtin_amdgcn_update_dpp(0, __float_as_int(x), 0x140, 0xF, 0xF, true)); // row mirror
    x += __shfl_xor(x, 16, 64);
    x += __shfl_xor(x, 32, 64);
    return x;
}

// ---------------- dtype detection ------------------------------------------
__global__ void k_detect(const void* __restrict__ att_rc, int* __restrict__ flagp) {
    __shared__ int cnt;
    if (threadIdx.x == 0) cnt = 0;
    __syncthreads();
    const unsigned short* w = (const unsigned short*)att_rc;
    int c = 0;
    for (int i = threadIdx.x; i < 8192; i += 256) {
        unsigned e = (w[i] >> 7) & 0xFF;
        if (e >= 0xC0) c++;
    }
    atomicAdd(&cnt, c);
    __syncthreads();
    if (threadIdx.x == 0) *flagp = (cnt > 8) ? 1 : 0;
}

// ---------------- CSR build ------------------------------------------------
__global__ void k_count(const int* __restrict__ dst, int* __restrict__ cnt) {
    int i = blockIdx.x * blockDim.x + threadIdx.x;
    int stride = gridDim.x * blockDim.x;
    for (int e = i; e < N_EDGES; e += stride) atomicAdd(&cnt[dst[e]], 1);
}

__global__ void k_scan(const int* __restrict__ cnt, int* __restrict__ rowptr,
                       int* __restrict__ cursor) {
    __shared__ int ts[1024];
    int t = threadIdx.x;
    const int CH = 49;   // 1024*49 >= 50000
    int b = t * CH, e = b + CH;
    if (b > N_NODES) b = N_NODES;
    if (e > N_NODES) e = N_NODES;
    int s = 0;
    for (int i = b; i < e; i++) s += cnt[i];
    ts[t] = s;
    __syncthreads();
    for (int off = 1; off < 1024; off <<= 1) {
        int v = (t >= off) ? ts[t - off] : 0;
        __syncthreads();
        ts[t] += v;
        __syncthreads();
    }
    int run = ts[t] - s;   // exclusive prefix
    for (int i = b; i < e; i++) { rowptr[i] = run; cursor[i] = run; run += cnt[i]; }
    if (t == 1023) rowptr[N_NODES] = run;
}

__global__ void k_fill(const int* __restrict__ src, const int* __restrict__ dst,
                       const int* __restrict__ etype, const int* __restrict__ rid,
                       const void* __restrict__ att_rc, const void* __restrict__ att_rp,
                       int* __restrict__ cursor, int* __restrict__ src_p,
                       int* __restrict__ tab_p, float* __restrict__ rcrp,
                       const int* __restrict__ flagp) {
    const int f32 = *flagp;
    int i = blockIdx.x * blockDim.x + threadIdx.x;
    int stride = gridDim.x * blockDim.x;
    for (int e = i; e < N_EDGES; e += stride) {
        int d = dst[e];
        int j = atomicAdd(&cursor[d], 1);
        src_p[j] = src[e];
        tab_p[j] = etype[e] | (rid[e] << 3);
        float* q = &rcrp[(size_t)j * 8];
        q[0] = LD(att_rc, 2 * (size_t)e, f32);
        q[1] = LD(att_rc, 2 * (size_t)e + 1, f32);
        q[2] = LD(att_rp, 3 * (size_t)e, f32);
        q[3] = LD(att_rp, 3 * (size_t)e + 1, f32);
        q[4] = LD(att_rp, 3 * (size_t)e + 2, f32);
    }
}

// ---------------- initial feature MLP (LDS-tiled, no shfl chains) ----------
__global__ void k_init(const void* __restrict__ feat,
                       const void* __restrict__ W0, const void* __restrict__ b0,
                       const void* __restrict__ W1, const void* __restrict__ b1,
                       float* __restrict__ feats, const int* __restrict__ flagp) {
    const int f32 = *flagp;
    __shared__ float sf[64 * 12];
    __shared__ float sW0[IN_DIM * 64];
    __shared__ float sb0[64], sb1[64];
    __shared__ float sh[64 * 64];
    __shared__ float sW1[64 * 64];
    int tid = threadIdx.x, n0 = blockIdx.x * 64;
    for (int i = tid; i < IN_DIM * 64; i += 256) sW0[i] = LD(W0, i, f32);
    for (int i = tid; i < 64; i += 256) { sb0[i] = LD(b0, i, f32); sb1[i] = LD(b1, i, f32); }
    for (int i = tid; i < 64 * 64; i += 256) sW1[i] = LD(W1, i, f32);
    for (int i = tid; i < 64 * IN_DIM; i += 256) {
        int n = n0 + i / IN_DIM, c = i % IN_DIM;
        sf[(i / IN_DIM) * 12 + c] = (n < N_NODES) ? LD(feat, (size_t)n * IN_DIM + c, f32) : 0.f;
    }
    __syncthreads();
    int ng = tid / 16, cg = tid % 16;
    float acc[4][4];
    #pragma unroll
    for (int i = 0; i < 4; i++)
        #pragma unroll
        for (int j = 0; j < 4; j++) acc[i][j] = sb0[cg * 4 + j];
    #pragma unroll
    for (int k = 0; k < IN_DIM; k++)
        #pragma unroll
        for (int i = 0; i < 4; i++) {
            float a = sf[(ng * 4 + i) * 12 + k];
            #pragma unroll
            for (int j = 0; j < 4; j++) acc[i][j] += a * sW0[k * 64 + cg * 4 + j];
        }
    #pragma unroll
    for (int i = 0; i < 4; i++)
        #pragma unroll
        for (int j = 0; j < 4; j++) sh[(ng * 4 + i) * 64 + cg * 4 + j] = fmaxf(acc[i][j], 0.f);
    __syncthreads();
    float o[4][4];
    #pragma unroll
    for (int i = 0; i < 4; i++)
        #pragma unroll
        for (int j = 0; j < 4; j++) o[i][j] = sb1[cg * 4 + j];
    for (int k4 = 0; k4 < 16; k4++) {
        float4 a4[4];
        #pragma unroll
        for (int i = 0; i < 4; i++) a4[i] = *(const float4*)&sh[(ng * 4 + i) * 64 + k4 * 4];
        #pragma unroll
        for (int kk = 0; kk < 4; kk++) {
            float4 bv = *(const float4*)&sW1[(k4 * 4 + kk) * 64 + cg * 4];
            #pragma unroll
            for (int i = 0; i < 4; i++) {
                float a = fcomp(a4[i], kk);
                o[i][0] += a * bv.x; o[i][1] += a * bv.y;
                o[i][2] += a * bv.z; o[i][3] += a * bv.w;
            }
        }
    }
    #pragma unroll
    for (int i = 0; i < 4; i++) {
        int n = n0 + ng * 4 + i;
        if (n < N_NODES) {
            float* r = feats + (size_t)n * F_TOT;
            #pragma unroll
            for (int j = 0; j < 4; j++) r[IN_DIM + cg * 4 + j] = o[i][j];
        }
    }
    for (int i = tid; i < 64 * IN_DIM; i += 256) {
        int n = n0 + i / IN_DIM, c = i % IN_DIM;
        if (n < N_NODES) feats[(size_t)n * F_TOT + c] = sf[(i / IN_DIM) * 12 + c];
    }
}

// ---------------- fused edge tables: T[l] = S @ W_fij[l] (+egat_bias) ------
__global__ void k_tables(const void* __restrict__ etype_emb, const void* __restrict__ rid_emb,
                         const void* __restrict__ rc_W, const void* __restrict__ rc_b,
                         const void* __restrict__ rp_W, const void* __restrict__ rp_b,
                         const void* __restrict__ W_fij, const void* __restrict__ egat_bias,
                         float* __restrict__ T, const int* __restrict__ flagp) {
    const int f32 = *flagp;
    int l = blockIdx.x;
    __shared__ float S[NT_ROWS * HID];
    __shared__ float W[HID * HO];
    for (int i = threadIdx.x; i < 7 * HID; i += 256) S[i] = LD(etype_emb, i, f32);
    for (int i = threadIdx.x; i < 31 * HID; i += 256) S[7 * HID + i] = LD(rid_emb, i, f32);
    for (int i = threadIdx.x; i < 2 * HID; i += 256) S[38 * HID + i] = LD(rc_W, i, f32);
    for (int i = threadIdx.x; i < 3 * HID; i += 256) S[40 * HID + i] = LD(rp_W, i, f32);
    for (int i = threadIdx.x; i < HID; i += 256)
        S[43 * HID + i] = LD(rc_b, i, f32) + LD(rp_b, i, f32);
    for (int i = threadIdx.x; i < HID * HO; i += 256)
        W[i] = LD(W_fij, (size_t)l * HID * HO + i, f32);
    __syncthreads();
    for (int idx = threadIdx.x; idx < NT_ROWS * HO; idx += 256) {
        int r = idx / HO, c = idx % HO;
        float acc = (r == 43) ? LD(egat_bias, l * HO + c, f32) : 0.f;
        for (int k = 0; k < HID; k++) acc += S[r * HID + k] * W[k * HO + c];
        T[(size_t)l * NT_ROWS * HO + idx] = acc;
    }
}

// ---------------- node GEMMs: f_ni/f_nj/hw = h @ {W_ni,W_nj,W_node} --------
__global__ void k_ngemm(const float* __restrict__ feats, int h_off,
                        const void* __restrict__ W_ni, const void* __restrict__ W_nj,
                        const void* __restrict__ W_node, int l,
                        float* __restrict__ f_ni, float* __restrict__ f_nj,
                        float* __restrict__ hw, const int* __restrict__ flagp) {
    const int f32 = *flagp;
    __shared__ float hs[64 * HID];
    __shared__ float ws[HID * HO];
    int n0 = blockIdx.x * 64;
    for (int i = threadIdx.x; i < 64 * HID; i += 256) {
        int n = n0 + i / HID;
        hs[i] = (n < N_NODES) ? feats[(size_t)n * F_TOT + h_off + (i % HID)] : 0.f;
    }
    const void* Wp[3] = {W_ni, W_nj, W_node};
    float* Op[3] = {f_ni, f_nj, hw};
    int ng = threadIdx.x / 16, cg = threadIdx.x % 16;
    for (int m = 0; m < 3; m++) {
        __syncthreads();
        for (int i = threadIdx.x; i < HID * HO; i += 256)
            ws[i] = LD(Wp[m], (size_t)l * HID * HO + i, f32);
        __syncthreads();
        float acc[4][8];
        #pragma unroll
        for (int i = 0; i < 4; i++)
            #pragma unroll
            for (int j = 0; j < 8; j++) acc[i][j] = 0.f;
        for (int k4 = 0; k4 < HID / 4; k4++) {
            float4 a4[4];
            #pragma unroll
            for (int i = 0; i < 4; i++) a4[i] = *(const float4*)&hs[(ng * 4 + i) * HID + k4 * 4];
            #pragma unroll
            for (int kk = 0; kk < 4; kk++) {
                float4 b0 = *(const float4*)&ws[(k4 * 4 + kk) * HO + cg * 8];
                float4 b1 = *(const float4*)&ws[(k4 * 4 + kk) * HO + cg * 8 + 4];
                #pragma unroll
                for (int i = 0; i < 4; i++) {
                    float a = fcomp(a4[i], kk);
                    acc[i][0] += a * b0.x; acc[i][1] += a * b0.y;
                    acc[i][2] += a * b0.z; acc[i][3] += a * b0.w;
                    acc[i][4] += a * b1.x; acc[i][5] += a * b1.y;
                    acc[i][6] += a * b1.z; acc[i][7] += a * b1.w;
                }
            }
        }
        #pragma unroll
        for (int i = 0; i < 4; i++) {
            int n = n0 + ng * 4 + i;
            if (n < N_NODES) {
                *(float4*)&Op[m][(size_t)n * HO + cg * 8] =
                    make_float4(acc[i][0], acc[i][1], acc[i][2], acc[i][3]);
                *(float4*)&Op[m][(size_t)n * HO + cg * 8 + 4] =
                    make_float4(acc[i][4], acc[i][5], acc[i][6], acc[i][7]);
            }
        }
    }
}

// ---------------- fused edge phase: logits + online softmax + aggregate ----
// one wave per dst node; h_att may alias f_nj (each row only used by its wave)
__global__ void __launch_bounds__(256) k_edge_fused(
        const float* __restrict__ T, const void* __restrict__ attn, int l,
        const float* __restrict__ f_ni, const float* __restrict__ f_nj,
        const float* __restrict__ hw, const int* __restrict__ rowptr,
        const int* __restrict__ src_p, const int* __restrict__ tab_p,
        const float* __restrict__ rcrp, float* __restrict__ h_att,
        const int* __restrict__ flagp) {
    const int f32 = *flagp;
    __shared__ float Ts[38 * HO];   // etype rows 0..6, rid rows 7..37
    const float* Tl = T + (size_t)l * NT_ROWS * HO;
    for (int i = threadIdx.x; i < 38 * HO; i += 256) Ts[i] = Tl[i];
    int lane = threadIdx.x & 63;
    float C0[6], C1[6];   // const rows 38..43 in registers
    #pragma unroll
    for (int r = 0; r < 6; r++) {
        C0[r] = Tl[(38 + r) * HO + lane];
        C1[r] = Tl[(38 + r) * HO + 64 + lane];
    }
    float AT0 = LD(attn, l * HO + lane, f32), AT1 = LD(attn, l * HO + 64 + lane, f32);
    __syncthreads();
    int d = blockIdx.x * 4 + (threadIdx.x >> 6);   // 12500*4 == 50000 exactly
    int jb = rowptr[d], je = rowptr[d + 1];
    float nj0 = f_nj[(size_t)d * HO + lane], nj1 = f_nj[(size_t)d * HO + 64 + lane];
    float m0 = -INFINITY, l0 = 0.f, a0 = 0.f;
    float m1 = -INFINITY, l1 = 0.f, a1 = 0.f;
    int s = 0, tp = 0;
    float rc0 = 0, rc1 = 0, rp0 = 0, rp1 = 0, rp2 = 0, ni0 = 0, ni1 = 0, h0 = 0, h1 = 0;
    if (jb < je) {
        s = src_p[jb]; tp = tab_p[jb];
        float4 q = *(const float4*)&rcrp[(size_t)jb * 8];
        rc0 = q.x; rc1 = q.y; rp0 = q.z; rp1 = q.w; rp2 = rcrp[(size_t)jb * 8 + 4];
        ni0 = f_ni[(size_t)s * HO + lane]; ni1 = f_ni[(size_t)s * HO + 64 + lane];
        h0 = hw[(size_t)s * HO + lane];    h1 = hw[(size_t)s * HO + 64 + lane];
    }
    for (int j = jb; j < je; j++) {
        int ctp = tp;
        float crc0 = rc0, crc1 = rc1, crp0 = rp0, crp1 = rp1, crp2 = rp2;
        float cni0 = ni0, cni1 = ni1, ch0 = h0, ch1 = h1;
        if (j + 1 < je) {   // prefetch next edge
            s = src_p[j + 1]; tp = tab_p[j + 1];
            float4 q = *(const float4*)&rcrp[(size_t)(j + 1) * 8];
            rc0 = q.x; rc1 = q.y; rp0 = q.z; rp1 = q.w; rp2 = rcrp[(size_t)(j + 1) * 8 + 4];
            ni0 = f_ni[(size_t)s * HO + lane]; ni1 = f_ni[(size_t)s * HO + 64 + lane];
            h0 = hw[(size_t)s * HO + lane];    h1 = hw[(size_t)s * HO + 64 + lane];
        }
        int et = ctp & 7, ri = ctp >> 3;
        float x0 = cni0 + nj0 + Ts[et * HO + lane] + Ts[(7 + ri) * HO + lane]
                 + crc0 * C0[0] + crc1 * C0[1] + crp0 * C0[2] + crp1 * C0[3]
                 + crp2 * C0[4] + C0[5];
        float x1 = cni1 + nj1 + Ts[et * HO + 64 + lane] + Ts[(7 + ri) * HO + 64 + lane]
                 + crc0 * C1[0] + crc1 * C1[1] + crp0 * C1[2] + crp1 * C1[3]
                 + crp2 * C1[4] + C1[5];
        x0 = (x0 > 0.f) ? x0 : NEG_SLOPE * x0;
        x1 = (x1 > 0.f) ? x1 : NEG_SLOPE * x1;
        float e0 = wsum(x0 * AT0), e1 = wsum(x1 * AT1);
        float nm0 = fmaxf(m0, e0), nm1 = fmaxf(m1, e1);
        float sc0 = __expf(m0 - nm0), sc1 = __expf(m1 - nm1);
        float w0 = __expf(e0 - nm0), w1 = __expf(e1 - nm1);
        l0 = l0 * sc0 + w0; a0 = a0 * sc0 + w0 * ch0; m0 = nm0;
        l1 = l1 * sc1 + w1; a1 = a1 * sc1 + w1 * ch1; m1 = nm1;
    }
    h_att[(size_t)d * HO + lane]      = a0 / (l0 + 1e-9f);
    h_att[(size_t)d * HO + 64 + lane] = a1 / (l1 + 1e-9f);
}

// ---------------- node MLP + residual: h_new = MLP2(h_att) + h_prev --------
__global__ void k_mlp(const float* __restrict__ h_att,
                      const void* __restrict__ Wm0, const void* __restrict__ bm0,
                      const void* __restrict__ Wm1, const void* __restrict__ bm1, int l,
                      float* __restrict__ feats, int prev_off, int out_off,
                      const int* __restrict__ flagp) {
    const int f32 = *flagp;
    __shared__ float xs[32 * HO];
    __shared__ float ys[32 * HO];
    __shared__ float ws[HO * 64];
    int n0 = blockIdx.x * 32;
    for (int i4 = threadIdx.x; i4 < 32 * HO / 4; i4 += 256) {
        int i = i4 * 4;
        int n = n0 + i / HO;
        if (n < N_NODES)
            *(float4*)&xs[i] = *(const float4*)&h_att[(size_t)n * HO + (i % HO)];
        else
            *(float4*)&xs[i] = make_float4(0.f, 0.f, 0.f, 0.f);
    }
    int ng = threadIdx.x / 16, cg = threadIdx.x % 16;
    for (int ch = 0; ch < 2; ch++) {
        __syncthreads();
        for (int i = threadIdx.x; i < HO * 64; i += 256) {
            int k = i / 64, c = i % 64;
            ws[i] = LD(Wm0, (size_t)l * HO * HO + k * HO + ch * 64 + c, f32);
        }
        __syncthreads();
        float acc[2][4];
        #pragma unroll
        for (int i = 0; i < 2; i++)
            #pragma unroll
            for (int j = 0; j < 4; j++)
                acc[i][j] = LD(bm0, l * HO + ch * 64 + cg * 4 + j, f32);
        for (int k4 = 0; k4 < HO / 4; k4++) {
            float4 a4[2];
            #pragma unroll
            for (int i = 0; i < 2; i++) a4[i] = *(const float4*)&xs[(ng * 2 + i) * HO + k4 * 4];
            #pragma unroll
            for (int kk = 0; kk < 4; kk++) {
                float4 bv = *(const float4*)&ws[(k4 * 4 + kk) * 64 + cg * 4];
                #pragma unroll
                for (int i = 0; i < 2; i++) {
                    float a = fcomp(a4[i], kk);
                    acc[i][0] += a * bv.x; acc[i][1] += a * bv.y;
                    acc[i][2] += a * bv.z; acc[i][3] += a * bv.w;
                }
            }
        }
        #pragma unroll
        for (int i = 0; i < 2; i++)
            *(float4*)&ys[(ng * 2 + i) * HO + ch * 64 + cg * 4] =
                make_float4(fmaxf(acc[i][0], 0.f), fmaxf(acc[i][1], 0.f),
                            fmaxf(acc[i][2], 0.f), fmaxf(acc[i][3], 0.f));
    }
    __syncthreads();
    for (int i = threadIdx.x; i < HO * 64; i += 256)
        ws[i] = LD(Wm1, (size_t)l * HO * 64 + i, f32);
    __syncthreads();
    float acc[2][4];
    #pragma unroll
    for (int i = 0; i < 2; i++)
        #pragma unroll
        for (int j = 0; j < 4; j++) acc[i][j] = LD(bm1, l * 64 + cg * 4 + j, f32);
    for (int k4 = 0; k4 < HO / 4; k4++) {
        float4 a4[2];
        #pragma unroll
        for (int i = 0; i < 2; i++) a4[i] = *(const float4*)&ys[(ng * 2 + i) * HO + k4 * 4];
        #pragma unroll
        for (int kk = 0; kk < 4; kk++) {
            float4 bv = *(const float4*)&ws[(k4 * 4 + kk) * 64 + cg * 4];
            #pragma unroll
            for (int i = 0; i < 2; i++) {
                float a = fcomp(a4[i], kk);
                acc[i][0] += a * bv.x; acc[i][1] += a * bv.y;
                acc[i][2] += a * bv.z; acc[i][3] += a * bv.w;
            }
        }
    }
    #pragma unroll
    for (int i = 0; i < 2; i++) {
        int n = n0 + ng * 2 + i;
        if (n < N_NODES) {
            float* r = feats + (size_t)n * F_TOT;
            #pragma unroll
            for (int j = 0; j < 4; j++)
                r[out_off + cg * 4 + j] = acc[i][j] + r[prev_off + cg * 4 + j];
        }
    }
}

// ---------------- graph max pool -------------------------------------------
__global__ void k_pool(const float* __restrict__ feats, unsigned* __restrict__ gmax) {
    int g = blockIdx.x;
    int chunk = blockIdx.y;
    int t = threadIdx.x;
    const int CS = (NPG + 15) / 16;
    int nb = chunk * CS;
    int ne = (nb + CS < NPG) ? nb + CS : NPG;
    float m0 = -INFINITY, m1 = -INFINITY;
    for (int n = nb; n < ne; n++) {
        const float* row = feats + (size_t)(g * NPG + n) * F_TOT;
        m0 = fmaxf(m0, row[t]);
        if (t + 256 < F_TOT) m1 = fmaxf(m1, row[t + 256]);
    }
    atomicMax(&gmax[g * F_TOT + t], fkey(m0));
    if (t + 256 < F_TOT) atomicMax(&gmax[g * F_TOT + t + 256], fkey(m1));
}

// ---------------- output write ---------------------------------------------
__global__ void k_out(const float* __restrict__ feats, const unsigned* __restrict__ gmax,
                      void* __restrict__ out, const int* __restrict__ flagp) {
    const int f32 = *flagp;
    size_t total = (size_t)B_GRAPHS * NPG * OUT_C;
    size_t stride = (size_t)gridDim.x * blockDim.x;
    for (size_t i = (size_t)blockIdx.x * blockDim.x + threadIdx.x; i < total; i += stride) {
        int c = (int)(i % OUT_C);
        size_t gn = i / OUT_C;
        int g = (int)(gn / NPG);
        float v = (c < F_TOT) ? feats[gn * F_TOT + c] : funkey(gmax[g * F_TOT + (c - F_TOT)]);
        if (f32) ((float*)out)[i] = v;
        else ((__hip_bfloat16*)out)[i] = __float2bfloat16(v);
    }
}

extern "C" void kernel_launch(void* const* d_in, const int* in_sizes, int n_in,
                              void* d_out, int out_size, void* d_ws, size_t ws_size,
                              hipStream_t stream) {
    const void* feat      = d_in[0];
    const void* att_rc    = d_in[1];
    const void* att_rp    = d_in[2];
    const void* etype_emb = d_in[3];
    const void* rid_emb   = d_in[4];
    const void* rc_W      = d_in[5];
    const void* rc_b      = d_in[6];
    const void* rp_W      = d_in[7];
    const void* rp_b      = d_in[8];
    const void* fe_W0     = d_in[9];
    const void* fe_b0     = d_in[10];
    const void* fe_W1     = d_in[11];
    const void* fe_b1     = d_in[12];
    const void* W_ni      = d_in[13];
    const void* W_nj      = d_in[14];
    const void* W_fij     = d_in[15];
    const void* W_node    = d_in[16];
    const void* attn      = d_in[17];
    const void* egat_bias = d_in[18];
    const void* Wm0       = d_in[19];
    const void* bm0       = d_in[20];
    const void* Wm1       = d_in[21];
    const void* bm1       = d_in[22];
    const int* src   = (const int*)d_in[23];
    const int* dst   = (const int*)d_in[24];
    const int* etype = (const int*)d_in[25];
    const int* rid   = (const int*)d_in[26];

    char* p = (char*)d_ws;
    auto alloc = [&](size_t bytes) {
        char* r = p;
        p += (bytes + 255) & ~(size_t)255;
        return r;
    };
    float*    feats  = (float*)alloc((size_t)N_NODES * F_TOT * 4);   // 53.2 MB
    float*    f_ni   = (float*)alloc((size_t)N_NODES * HO * 4);      // 25.6 MB
    float*    f_nj   = (float*)alloc((size_t)N_NODES * HO * 4);      // 25.6 MB (aliased h_att)
    float*    hw     = (float*)alloc((size_t)N_NODES * HO * 4);      // 25.6 MB
    float*    T      = (float*)alloc((size_t)3 * NT_ROWS * HO * 4);
    unsigned* gmax   = (unsigned*)alloc((size_t)B_GRAPHS * F_TOT * 4);
    int*      flagp  = (int*)alloc(256);
    int*      rowptr = (int*)alloc((size_t)(N_NODES + 1) * 4);
    int*      cursor = (int*)alloc((size_t)N_NODES * 4);
    int*      cnt    = (int*)alloc((size_t)N_NODES * 4);
    int*      src_p  = (int*)alloc((size_t)N_EDGES * 4);             // 2 MB
    int*      tab_p  = (int*)alloc((size_t)N_EDGES * 4);             // 2 MB
    float*    rcrp   = (float*)alloc((size_t)N_EDGES * 8 * 4);       // 16 MB
    float*    h_att  = f_nj;   // alias: f_nj[d] only read by wave d before write

    k_detect<<<1, 256, 0, stream>>>(att_rc, flagp);
    hipMemsetAsync(cnt, 0, (size_t)N_NODES * 4, stream);
    hipMemsetAsync(gmax, 0, (size_t)B_GRAPHS * F_TOT * 4, stream);
    k_count<<<512, 256, 0, stream>>>(dst, cnt);
    k_scan<<<1, 1024, 0, stream>>>(cnt, rowptr, cursor);
    k_fill<<<1024, 256, 0, stream>>>(src, dst, etype, rid, att_rc, att_rp,
                                     cursor, src_p, tab_p, rcrp, flagp);
    k_init<<<(N_NODES + 63) / 64, 256, 0, stream>>>(feat, fe_W0, fe_b0, fe_W1, fe_b1,
                                                    feats, flagp);
    k_tables<<<3, 256, 0, stream>>>(etype_emb, rid_emb, rc_W, rc_b, rp_W, rp_b,
                                    W_fij, egat_bias, T, flagp);
    for (int l = 0; l < 3; l++) {
        int h_off = IN_DIM + l * HID;
        int out_off = IN_DIM + (l + 1) * HID;
        k_ngemm<<<(N_NODES + 63) / 64, 256, 0, stream>>>(feats, h_off, W_ni, W_nj, W_node, l,
                                                         f_ni, f_nj, hw, flagp);
        k_edge_fused<<<N_NODES / 4, 256, 0, stream>>>(T, attn, l, f_ni, f_nj, hw,
                                                      rowptr, src_p, tab_p, rcrp,
                                                      h_att, flagp);
        k_mlp<<<(N_NODES + 31) / 32, 256, 0, stream>>>(h_att, Wm0, bm0, Wm1, bm1, l,
                                                       feats, h_off, out_off, flagp);
    }
    k_pool<<<dim3(B_GRAPHS, 16), 256, 0, stream>>>(feats, gmax);
    k_out<<<4096, 256, 0, stream>>>(feats, gmax, d_out, flagp);
}

// Round 4
// 1426.058 us; speedup vs baseline: 2.5059x; 2.5059x over previous
//
#include <hip/hip_runtime.h>
#include <hip/hip_bf16.h>
#include <math.h>

#define N_NODES 50000
#define N_EDGES 500000
#define B_GRAPHS 8
#define NPG 6250
#define HID 64
#define HO 128          // HEADS*HID
#define IN_DIM 10
#define F_TOT 266       // IN_DIM + 4*HID
#define OUT_C 532       // 2*F_TOT
#define NEG_SLOPE 0.2f
#define NT_ROWS 44      // 7 etype + 31 rid + 2 rc + 3 rp + 1 const

// dtype-agnostic float load: f32 flag chooses fp32 or bf16 interpretation
__device__ __forceinline__ float LD(const void* p, size_t i, int f32) {
    if (f32) return ((const float*)p)[i];
    unsigned u = ((const unsigned short*)p)[i];
    return __uint_as_float(u << 16);
}
// monotone float<->uint key for atomicMax on floats (memset-0 == -infinity)
__device__ __forceinline__ unsigned fkey(float f) {
    unsigned b = __float_as_uint(f);
    return (b & 0x80000000u) ? ~b : (b | 0x80000000u);
}
__device__ __forceinline__ float funkey(unsigned k) {
    unsigned b = (k & 0x80000000u) ? (k & 0x7fffffffu) : ~k;
    return __uint_as_float(b);
}
// bf16 RNE pack/unpack pairs
__device__ __forceinline__ unsigned short rnebf(float x) {
    unsigned u = __float_as_uint(x);
    return (unsigned short)((u + 0x7FFFu + ((u >> 16) & 1u)) >> 16);
}
__device__ __forceinline__ unsigned pk2(float lo, float hi) {
    return (unsigned)rnebf(lo) | ((unsigned)rnebf(hi) << 16);
}
__device__ __forceinline__ float plo(unsigned u) { return __uint_as_float(u << 16); }
__device__ __forceinline__ float phi(unsigned u) { return __uint_as_float(u & 0xFFFF0000u); }
// wave64 sum: 4 DPP steps (VALU pipe), then 2 shfl across rows
__device__ __forceinline__ float wsum(float x) {
    x += __int_as_float(__builtin_amdgcn_update_dpp(0, __float_as_int(x), 0xB1, 0xF, 0xF, true));
    x += __int_as_float(__builtin_amdgcn_update_dpp(0, __float_as_int(x), 0x4E, 0xF, 0xF, true));
    x += __int_as_float(__builtin_amdgcn_update_dpp(0, __float_as_int(x), 0x141, 0xF, 0xF, true));
    x += __int_as_float(__builtin_amdgcn_update_dpp(0, __float_as_int(x), 0x140, 0xF, 0xF, true));
    x += __shfl_xor(x, 16, 64);
    x += __shfl_xor(x, 32, 64);
    return x;
}

// ---------------- dtype detection ------------------------------------------
__global__ void k_detect(const void* __restrict__ att_rc, int* __restrict__ flagp) {
    __shared__ int cnt;
    if (threadIdx.x == 0) cnt = 0;
    __syncthreads();
    const unsigned short* w = (const unsigned short*)att_rc;
    int c = 0;
    for (int i = threadIdx.x; i < 8192; i += 256) {
        unsigned e = (w[i] >> 7) & 0xFF;
        if (e >= 0xC0) c++;
    }
    atomicAdd(&cnt, c);
    __syncthreads();
    if (threadIdx.x == 0) *flagp = (cnt > 8) ? 1 : 0;
}

// ---------------- CSR build ------------------------------------------------
__global__ void k_count(const int* __restrict__ dst, int* __restrict__ cnt) {
    int i = blockIdx.x * blockDim.x + threadIdx.x;
    int stride = gridDim.x * blockDim.x;
    for (int e = i; e < N_EDGES; e += stride) atomicAdd(&cnt[dst[e]], 1);
}

__global__ void k_scan(const int* __restrict__ cnt, int* __restrict__ rowptr,
                       int* __restrict__ cursor) {
    __shared__ int ts[1024];
    int t = threadIdx.x;
    const int CH = 49;
    int b = t * CH, e = b + CH;
    if (b > N_NODES) b = N_NODES;
    if (e > N_NODES) e = N_NODES;
    int s = 0;
    for (int i = b; i < e; i++) s += cnt[i];
    ts[t] = s;
    __syncthreads();
    for (int off = 1; off < 1024; off <<= 1) {
        int v = (t >= off) ? ts[t - off] : 0;
        __syncthreads();
        ts[t] += v;
        __syncthreads();
    }
    int run = ts[t] - s;
    for (int i = b; i < e; i++) { rowptr[i] = run; cursor[i] = run; run += cnt[i]; }
    if (t == 1023) rowptr[N_NODES] = run;
}

__global__ void k_fill(const int* __restrict__ src, const int* __restrict__ dst,
                       const int* __restrict__ etype, const int* __restrict__ rid,
                       const void* __restrict__ att_rc, const void* __restrict__ att_rp,
                       int* __restrict__ cursor, int* __restrict__ src_p,
                       uint4* __restrict__ emeta, const int* __restrict__ flagp) {
    const int f32 = *flagp;
    int i = blockIdx.x * blockDim.x + threadIdx.x;
    int stride = gridDim.x * blockDim.x;
    for (int e = i; e < N_EDGES; e += stride) {
        int d = dst[e];
        int j = atomicAdd(&cursor[d], 1);
        src_p[j] = src[e];
        float rc0 = LD(att_rc, 2 * (size_t)e, f32), rc1 = LD(att_rc, 2 * (size_t)e + 1, f32);
        float rp0 = LD(att_rp, 3 * (size_t)e, f32), rp1 = LD(att_rp, 3 * (size_t)e + 1, f32),
              rp2 = LD(att_rp, 3 * (size_t)e + 2, f32);
        uint4 m;
        m.x = pk2(rc0, rc1);
        m.y = pk2(rp0, rp1);
        m.z = pk2(rp2, 0.f);
        m.w = (unsigned)(etype[e] | (rid[e] << 3));
        emeta[j] = m;
    }
}

// ---------------- initial feature MLP --------------------------------------
__global__ void k_init(const void* __restrict__ feat,
                       const void* __restrict__ W0, const void* __restrict__ b0,
                       const void* __restrict__ W1, const void* __restrict__ b1,
                       float* __restrict__ feats, const int* __restrict__ flagp) {
    const int f32 = *flagp;
    __shared__ float sf[64 * 12];
    __shared__ float sW0[IN_DIM * 64];
    __shared__ float sb0[64], sb1[64];
    __shared__ float sh[64 * 64];
    __shared__ float sW1[64 * 64];
    int tid = threadIdx.x, n0 = blockIdx.x * 64;
    for (int i = tid; i < IN_DIM * 64; i += 256) sW0[i] = LD(W0, i, f32);
    for (int i = tid; i < 64; i += 256) { sb0[i] = LD(b0, i, f32); sb1[i] = LD(b1, i, f32); }
    for (int i = tid; i < 64 * 64; i += 256) sW1[i] = LD(W1, i, f32);
    for (int i = tid; i < 64 * IN_DIM; i += 256) {
        int n = n0 + i / IN_DIM, c = i % IN_DIM;
        sf[(i / IN_DIM) * 12 + c] = (n < N_NODES) ? LD(feat, (size_t)n * IN_DIM + c, f32) : 0.f;
    }
    __syncthreads();
    int ng = tid / 16, cg = tid % 16;
    float acc[4][4];
    #pragma unroll
    for (int i = 0; i < 4; i++)
        #pragma unroll
        for (int j = 0; j < 4; j++) acc[i][j] = sb0[cg * 4 + j];
    #pragma unroll
    for (int k = 0; k < IN_DIM; k++)
        #pragma unroll
        for (int i = 0; i < 4; i++) {
            float a = sf[(ng * 4 + i) * 12 + k];
            #pragma unroll
            for (int j = 0; j < 4; j++) acc[i][j] += a * sW0[k * 64 + cg * 4 + j];
        }
    #pragma unroll
    for (int i = 0; i < 4; i++)
        #pragma unroll
        for (int j = 0; j < 4; j++) sh[(ng * 4 + i) * 64 + cg * 4 + j] = fmaxf(acc[i][j], 0.f);
    __syncthreads();
    float o[4][4];
    #pragma unroll
    for (int i = 0; i < 4; i++)
        #pragma unroll
        for (int j = 0; j < 4; j++) o[i][j] = sb1[cg * 4 + j];
    for (int k = 0; k < 64; k++) {
        float4 bv = *(const float4*)&sW1[k * 64 + cg * 4];
        #pragma unroll
        for (int i = 0; i < 4; i++) {
            float a = sh[(ng * 4 + i) * 64 + k];
            o[i][0] += a * bv.x; o[i][1] += a * bv.y;
            o[i][2] += a * bv.z; o[i][3] += a * bv.w;
        }
    }
    #pragma unroll
    for (int i = 0; i < 4; i++) {
        int n = n0 + ng * 4 + i;
        if (n < N_NODES) {
            float* r = feats + (size_t)n * F_TOT;
            #pragma unroll
            for (int j = 0; j < 4; j++) r[IN_DIM + cg * 4 + j] = o[i][j];
        }
    }
    for (int i = tid; i < 64 * IN_DIM; i += 256) {
        int n = n0 + i / IN_DIM, c = i % IN_DIM;
        if (n < N_NODES) feats[(size_t)n * F_TOT + c] = sf[(i / IN_DIM) * 12 + c];
    }
}

// ---------------- fused edge tables ----------------------------------------
__global__ void k_tables(const void* __restrict__ etype_emb, const void* __restrict__ rid_emb,
                         const void* __restrict__ rc_W, const void* __restrict__ rc_b,
                         const void* __restrict__ rp_W, const void* __restrict__ rp_b,
                         const void* __restrict__ W_fij, const void* __restrict__ egat_bias,
                         float* __restrict__ T, const int* __restrict__ flagp) {
    const int f32 = *flagp;
    int l = blockIdx.x;
    __shared__ float S[NT_ROWS * HID];
    __shared__ float W[HID * HO];
    for (int i = threadIdx.x; i < 7 * HID; i += 256) S[i] = LD(etype_emb, i, f32);
    for (int i = threadIdx.x; i < 31 * HID; i += 256) S[7 * HID + i] = LD(rid_emb, i, f32);
    for (int i = threadIdx.x; i < 2 * HID; i += 256) S[38 * HID + i] = LD(rc_W, i, f32);
    for (int i = threadIdx.x; i < 3 * HID; i += 256) S[40 * HID + i] = LD(rp_W, i, f32);
    for (int i = threadIdx.x; i < HID; i += 256)
        S[43 * HID + i] = LD(rc_b, i, f32) + LD(rp_b, i, f32);
    for (int i = threadIdx.x; i < HID * HO; i += 256)
        W[i] = LD(W_fij, (size_t)l * HID * HO + i, f32);
    __syncthreads();
    for (int idx = threadIdx.x; idx < NT_ROWS * HO; idx += 256) {
        int r = idx / HO, c = idx % HO;
        float acc = (r == 43) ? LD(egat_bias, l * HO + c, f32) : 0.f;
        for (int k = 0; k < HID; k++) acc += S[r * HID + k] * W[k * HO + c];
        T[(size_t)l * NT_ROWS * HO + idx] = acc;
    }
}

// ---------------- node GEMMs -> packed bf16 gather buffers ------------------
// gsrc[n*128 + c*2]   = pk(f_ni[n][c], f_ni[n][c+64])
// gsrc[n*128 + c*2+1] = pk(hw[n][c],   hw[n][c+64])
// gdst[n*64  + c]     = pk(f_nj[n][c], f_nj[n][c+64])
__global__ void __launch_bounds__(256) k_ngemm(
        const float* __restrict__ feats, int h_off,
        const void* __restrict__ W_ni, const void* __restrict__ W_nj,
        const void* __restrict__ W_node, int l,
        unsigned* __restrict__ gsrc, unsigned* __restrict__ gdst,
        const int* __restrict__ flagp) {
    const int f32 = *flagp;
    __shared__ float hs[64 * 68];      // 17 KB, padded stride
    __shared__ unsigned sw[3 * 4096];  // 48 KB: [m][k][pc] bf16 pairs (c, c+64)
    int tid = threadIdx.x, n0 = blockIdx.x * 64;
    for (int i = tid; i < 64 * 64; i += 256) {
        int n = i >> 6, c = i & 63;
        int gn = n0 + n;
        hs[n * 68 + c] = (gn < N_NODES) ? feats[(size_t)gn * F_TOT + h_off + c] : 0.f;
    }
    for (int i = tid; i < 3 * 4096; i += 256) {
        int m = i >> 12, r = i & 4095;
        int k = r >> 6, pc = r & 63;
        const void* W = (m == 0) ? W_ni : (m == 1) ? W_nj : W_node;
        sw[i] = pk2(LD(W, (size_t)l * HID * HO + k * HO + pc, f32),
                    LD(W, (size_t)l * HID * HO + k * HO + pc + 64, f32));
    }
    __syncthreads();
    int ng = tid >> 4, cg = tid & 15;   // 16 node-groups x 4 nodes; 16 col-groups x 4 pair-cols
    for (int m = 0; m < 3; m++) {
        float aL[4][4], aH[4][4];
        #pragma unroll
        for (int i = 0; i < 4; i++)
            #pragma unroll
            for (int j = 0; j < 4; j++) { aL[i][j] = 0.f; aH[i][j] = 0.f; }
        for (int k = 0; k < HID; k++) {
            uint4 w = *(const uint4*)&sw[m * 4096 + k * 64 + cg * 4];
            float wL[4] = {plo(w.x), plo(w.y), plo(w.z), plo(w.w)};
            float wH[4] = {phi(w.x), phi(w.y), phi(w.z), phi(w.w)};
            #pragma unroll
            for (int i = 0; i < 4; i++) {
                float a = hs[(ng * 4 + i) * 68 + k];
                #pragma unroll
                for (int j = 0; j < 4; j++) { aL[i][j] += a * wL[j]; aH[i][j] += a * wH[j]; }
            }
        }
        #pragma unroll
        for (int i = 0; i < 4; i++) {
            int gn = n0 + ng * 4 + i;
            if (gn < N_NODES) {
                #pragma unroll
                for (int j = 0; j < 4; j++) {
                    int pc = cg * 4 + j;
                    unsigned v = pk2(aL[i][j], aH[i][j]);
                    if (m == 1) gdst[(size_t)gn * 64 + pc] = v;
                    else gsrc[(size_t)gn * 128 + pc * 2 + (m == 2 ? 1 : 0)] = v;
                }
            }
        }
    }
}

// ---------------- fused edge phase: logits + online softmax + aggregate ----
__global__ void __launch_bounds__(256) k_edge_fused(
        const float* __restrict__ T, const void* __restrict__ attn, int l,
        const unsigned* __restrict__ gsrc, const unsigned* __restrict__ gdst,
        const int* __restrict__ rowptr, const int* __restrict__ src_p,
        const uint4* __restrict__ emeta, float* __restrict__ h_att,
        const int* __restrict__ flagp) {
    const int f32 = *flagp;
    __shared__ float Ts[38 * HO];   // 19 KB
    const float* Tl = T + (size_t)l * NT_ROWS * HO;
    for (int i4 = threadIdx.x; i4 < 38 * HO / 4; i4 += 256)
        ((float4*)Ts)[i4] = ((const float4*)Tl)[i4];
    int lane = threadIdx.x & 63;
    float C0[6], C1[6];
    #pragma unroll
    for (int r = 0; r < 6; r++) {
        C0[r] = Tl[(38 + r) * HO + lane];
        C1[r] = Tl[(38 + r) * HO + 64 + lane];
    }
    float AT0 = LD(attn, l * HO + lane, f32), AT1 = LD(attn, l * HO + 64 + lane, f32);
    __syncthreads();
    int d = blockIdx.x * 4 + (threadIdx.x >> 6);
    int jb = rowptr[d], je = rowptr[d + 1];
    unsigned gd = gdst[(size_t)d * 64 + lane];
    float nj0 = plo(gd), nj1 = phi(gd);
    float m0 = -INFINITY, l0 = 0.f, a0 = 0.f;
    float m1 = -INFINITY, l1 = 0.f, a1 = 0.f;
    int sn = 0; uint4 em = make_uint4(0, 0, 0, 0); uint2 g = make_uint2(0, 0);
    if (jb < je) {
        sn = src_p[jb]; em = emeta[jb];
        g = *(const uint2*)&gsrc[(size_t)sn * 128 + lane * 2];
    }
    for (int j = jb; j < je; j++) {
        unsigned tab = em.w;
        float rc0 = plo(em.x), rc1 = phi(em.x);
        float rp0 = plo(em.y), rp1 = phi(em.y), rp2 = plo(em.z);
        float ni0 = plo(g.x), ni1 = phi(g.x);
        float h0 = plo(g.y), h1 = phi(g.y);
        if (j + 1 < je) {   // prefetch next edge
            sn = src_p[j + 1]; em = emeta[j + 1];
            g = *(const uint2*)&gsrc[(size_t)sn * 128 + lane * 2];
        }
        int et = tab & 7, ri = (int)(tab >> 3);
        float x0 = ni0 + nj0 + Ts[et * HO + lane] + Ts[(7 + ri) * HO + lane]
                 + rc0 * C0[0] + rc1 * C0[1] + rp0 * C0[2] + rp1 * C0[3]
                 + rp2 * C0[4] + C0[5];
        float x1 = ni1 + nj1 + Ts[et * HO + 64 + lane] + Ts[(7 + ri) * HO + 64 + lane]
                 + rc0 * C1[0] + rc1 * C1[1] + rp0 * C1[2] + rp1 * C1[3]
                 + rp2 * C1[4] + C1[5];
        x0 = (x0 > 0.f) ? x0 : NEG_SLOPE * x0;
        x1 = (x1 > 0.f) ? x1 : NEG_SLOPE * x1;
        float e0 = wsum(x0 * AT0), e1 = wsum(x1 * AT1);
        float nm0 = fmaxf(m0, e0), nm1 = fmaxf(m1, e1);
        float sc0 = __expf(m0 - nm0), sc1 = __expf(m1 - nm1);
        float w0 = __expf(e0 - nm0), w1 = __expf(e1 - nm1);
        l0 = l0 * sc0 + w0; a0 = a0 * sc0 + w0 * h0; m0 = nm0;
        l1 = l1 * sc1 + w1; a1 = a1 * sc1 + w1 * h1; m1 = nm1;
    }
    h_att[(size_t)d * HO + lane]      = a0 / (l0 + 1e-9f);
    h_att[(size_t)d * HO + 64 + lane] = a1 / (l1 + 1e-9f);
}

// ---------------- node MLP + residual --------------------------------------
// 32 nodes/block; weights staged ONCE as bf16; y round-trips through xy.
__global__ void __launch_bounds__(256) k_mlp(
        const float* __restrict__ h_att,
        const void* __restrict__ Wm0, const void* __restrict__ bm0,
        const void* __restrict__ Wm1, const void* __restrict__ bm1, int l,
        float* __restrict__ feats, int prev_off, int out_off,
        const int* __restrict__ flagp) {
    const int f32 = *flagp;
    __shared__ unsigned sw0[HO * 64];        // 32 KB: [k][pc] pairs (c, c+64)
    __shared__ unsigned short sw1[HO * 64];  // 16 KB: [k][oc]
    __shared__ float xy[32 * 132];           // 16.5 KB padded
    __shared__ float sb0[HO], sb1[64];
    int tid = threadIdx.x, n0 = blockIdx.x * 32;
    for (int i = tid; i < HO * 64; i += 256) {
        int k = i >> 6, pc = i & 63;
        sw0[i] = pk2(LD(Wm0, (size_t)l * HO * HO + k * HO + pc, f32),
                     LD(Wm0, (size_t)l * HO * HO + k * HO + pc + 64, f32));
    }
    for (int i = tid; i < HO * 64; i += 256)
        sw1[i] = rnebf(LD(Wm1, (size_t)l * HO * 64 + i, f32));
    for (int i = tid; i < HO; i += 256) sb0[i] = LD(bm0, l * HO + i, f32);
    for (int i = tid; i < 64; i += 256) sb1[i] = LD(bm1, l * 64 + i, f32);
    for (int i4 = tid; i4 < 32 * 32; i4 += 256) {
        int n = i4 >> 5, c = (i4 & 31) * 4;
        int gn = n0 + n;
        *(float4*)&xy[n * 132 + c] = (gn < N_NODES)
            ? *(const float4*)&h_att[(size_t)gn * HO + c]
            : make_float4(0.f, 0.f, 0.f, 0.f);
    }
    __syncthreads();
    int nn = (tid >> 4) * 2, cg = tid & 15;   // 2 nodes/thread, 4 pair-cols
    float yL[2][4], yH[2][4];
    #pragma unroll
    for (int i = 0; i < 2; i++)
        #pragma unroll
        for (int j = 0; j < 4; j++) {
            yL[i][j] = sb0[cg * 4 + j];
            yH[i][j] = sb0[cg * 4 + j + 64];
        }
    for (int k = 0; k < HO; k++) {
        uint4 w = *(const uint4*)&sw0[k * 64 + cg * 4];
        float wL[4] = {plo(w.x), plo(w.y), plo(w.z), plo(w.w)};
        float wH[4] = {phi(w.x), phi(w.y), phi(w.z), phi(w.w)};
        float a0 = xy[nn * 132 + k], a1 = xy[(nn + 1) * 132 + k];
        #pragma unroll
        for (int j = 0; j < 4; j++) {
            yL[0][j] += a0 * wL[j]; yH[0][j] += a0 * wH[j];
            yL[1][j] += a1 * wL[j]; yH[1][j] += a1 * wH[j];
        }
    }
    __syncthreads();   // all stage-A reads of xy complete
    #pragma unroll
    for (int i = 0; i < 2; i++)
        #pragma unroll
        for (int j = 0; j < 4; j++) {
            xy[(nn + i) * 132 + cg * 4 + j]      = fmaxf(yL[i][j], 0.f);
            xy[(nn + i) * 132 + 64 + cg * 4 + j] = fmaxf(yH[i][j], 0.f);
        }
    __syncthreads();
    float o[2][4];
    #pragma unroll
    for (int i = 0; i < 2; i++)
        #pragma unroll
        for (int j = 0; j < 4; j++) o[i][j] = sb1[cg * 4 + j];
    for (int k = 0; k < HO; k++) {
        uint2 w2 = *(const uint2*)&sw1[k * 64 + cg * 4];
        float w0 = __uint_as_float(w2.x << 16);
        float w1 = __uint_as_float(w2.x & 0xFFFF0000u);
        float w2f = __uint_as_float(w2.y << 16);
        float w3 = __uint_as_float(w2.y & 0xFFFF0000u);
        float a0 = xy[nn * 132 + k], a1 = xy[(nn + 1) * 132 + k];
        o[0][0] += a0 * w0; o[0][1] += a0 * w1; o[0][2] += a0 * w2f; o[0][3] += a0 * w3;
        o[1][0] += a1 * w0; o[1][1] += a1 * w1; o[1][2] += a1 * w2f; o[1][3] += a1 * w3;
    }
    #pragma unroll
    for (int i = 0; i < 2; i++) {
        int gn = n0 + nn + i;
        if (gn < N_NODES) {
            float* r = feats + (size_t)gn * F_TOT;
            #pragma unroll
            for (int j = 0; j < 4; j++)
                r[out_off + cg * 4 + j] = o[i][j] + r[prev_off + cg * 4 + j];
        }
    }
}

// ---------------- graph max pool -------------------------------------------
__global__ void k_pool(const float* __restrict__ feats, unsigned* __restrict__ gmax) {
    int g = blockIdx.x;
    int chunk = blockIdx.y;
    int t = threadIdx.x;
    const int CS = (NPG + 15) / 16;
    int nb = chunk * CS;
    int ne = (nb + CS < NPG) ? nb + CS : NPG;
    float m0 = -INFINITY, m1 = -INFINITY;
    for (int n = nb; n < ne; n++) {
        const float* row = feats + (size_t)(g * NPG + n) * F_TOT;
        m0 = fmaxf(m0, row[t]);
        if (t + 256 < F_TOT) m1 = fmaxf(m1, row[t + 256]);
    }
    atomicMax(&gmax[g * F_TOT + t], fkey(m0));
    if (t + 256 < F_TOT) atomicMax(&gmax[g * F_TOT + t + 256], fkey(m1));
}

// ---------------- output write ---------------------------------------------
__global__ void k_out(const float* __restrict__ feats, const unsigned* __restrict__ gmax,
                      void* __restrict__ out, const int* __restrict__ flagp) {
    const int f32 = *flagp;
    size_t total = (size_t)B_GRAPHS * NPG * OUT_C;
    size_t stride = (size_t)gridDim.x * blockDim.x;
    for (size_t i = (size_t)blockIdx.x * blockDim.x + threadIdx.x; i < total; i += stride) {
        int c = (int)(i % OUT_C);
        size_t gn = i / OUT_C;
        int g = (int)(gn / NPG);
        float v = (c < F_TOT) ? feats[gn * F_TOT + c] : funkey(gmax[g * F_TOT + (c - F_TOT)]);
        if (f32) ((float*)out)[i] = v;
        else ((__hip_bfloat16*)out)[i] = __float2bfloat16(v);
    }
}

extern "C" void kernel_launch(void* const* d_in, const int* in_sizes, int n_in,
                              void* d_out, int out_size, void* d_ws, size_t ws_size,
                              hipStream_t stream) {
    const void* feat      = d_in[0];
    const void* att_rc    = d_in[1];
    const void* att_rp    = d_in[2];
    const void* etype_emb = d_in[3];
    const void* rid_emb   = d_in[4];
    const void* rc_W      = d_in[5];
    const void* rc_b      = d_in[6];
    const void* rp_W      = d_in[7];
    const void* rp_b      = d_in[8];
    const void* fe_W0     = d_in[9];
    const void* fe_b0     = d_in[10];
    const void* fe_W1     = d_in[11];
    const void* fe_b1     = d_in[12];
    const void* W_ni      = d_in[13];
    const void* W_nj      = d_in[14];
    const void* W_fij     = d_in[15];
    const void* W_node    = d_in[16];
    const void* attn      = d_in[17];
    const void* egat_bias = d_in[18];
    const void* Wm0       = d_in[19];
    const void* bm0       = d_in[20];
    const void* Wm1       = d_in[21];
    const void* bm1       = d_in[22];
    const int* src   = (const int*)d_in[23];
    const int* dst   = (const int*)d_in[24];
    const int* etype = (const int*)d_in[25];
    const int* rid   = (const int*)d_in[26];

    char* p = (char*)d_ws;
    auto alloc = [&](size_t bytes) {
        char* r = p;
        p += (bytes + 255) & ~(size_t)255;
        return r;
    };
    float*    feats  = (float*)alloc((size_t)N_NODES * F_TOT * 4);    // 53.2 MB
    unsigned* gsrc   = (unsigned*)alloc((size_t)N_NODES * HO * 4);    // 25.6 MB
    unsigned* gdst   = (unsigned*)alloc((size_t)N_NODES * 64 * 4);    // 12.8 MB
    float*    h_att  = (float*)alloc((size_t)N_NODES * HO * 4);       // 25.6 MB
    float*    T      = (float*)alloc((size_t)3 * NT_ROWS * HO * 4);
    unsigned* gmax   = (unsigned*)alloc((size_t)B_GRAPHS * F_TOT * 4);
    int*      flagp  = (int*)alloc(256);
    int*      rowptr = (int*)alloc((size_t)(N_NODES + 1) * 4);
    int*      cursor = (int*)alloc((size_t)N_NODES * 4);
    int*      cnt    = (int*)alloc((size_t)N_NODES * 4);
    int*      src_p  = (int*)alloc((size_t)N_EDGES * 4);              // 2 MB
    uint4*    emeta  = (uint4*)alloc((size_t)N_EDGES * 16);           // 8 MB

    k_detect<<<1, 256, 0, stream>>>(att_rc, flagp);
    hipMemsetAsync(cnt, 0, (size_t)N_NODES * 4, stream);
    hipMemsetAsync(gmax, 0, (size_t)B_GRAPHS * F_TOT * 4, stream);
    k_count<<<512, 256, 0, stream>>>(dst, cnt);
    k_scan<<<1, 1024, 0, stream>>>(cnt, rowptr, cursor);
    k_fill<<<1024, 256, 0, stream>>>(src, dst, etype, rid, att_rc, att_rp,
                                     cursor, src_p, emeta, flagp);
    k_init<<<(N_NODES + 63) / 64, 256, 0, stream>>>(feat, fe_W0, fe_b0, fe_W1, fe_b1,
                                                    feats, flagp);
    k_tables<<<3, 256, 0, stream>>>(etype_emb, rid_emb, rc_W, rc_b, rp_W, rp_b,
                                    W_fij, egat_bias, T, flagp);
    for (int l = 0; l < 3; l++) {
        int h_off = IN_DIM + l * HID;
        int out_off = IN_DIM + (l + 1) * HID;
        k_ngemm<<<(N_NODES + 63) / 64, 256, 0, stream>>>(feats, h_off, W_ni, W_nj, W_node, l,
                                                         gsrc, gdst, flagp);
        k_edge_fused<<<N_NODES / 4, 256, 0, stream>>>(T, attn, l, gsrc, gdst,
                                                      rowptr, src_p, emeta, h_att, flagp);
        k_mlp<<<(N_NODES + 31) / 32, 256, 0, stream>>>(h_att, Wm0, bm0, Wm1, bm1, l,
                                                       feats, h_off, out_off, flagp);
    }
    k_pool<<<dim3(B_GRAPHS, 16), 256, 0, stream>>>(feats, gmax);
    k_out<<<4096, 256, 0, stream>>>(feats, gmax, d_out, flagp);
}

// Round 5
// 1350.774 us; speedup vs baseline: 2.6455x; 1.0557x over previous
//
#include <hip/hip_runtime.h>
#include <hip/hip_bf16.h>
#include <math.h>

#define N_NODES 50000
#define N_EDGES 500000
#define B_GRAPHS 8
#define NPG 6250
#define HID 64
#define HO 128          // HEADS*HID
#define IN_DIM 10
#define F_TOT 266       // IN_DIM + 4*HID
#define OUT_C 532       // 2*F_TOT
#define NEG_SLOPE 0.2f
#define NT_ROWS 44      // 7 etype + 31 rid + 2 rc + 3 rp + 1 const

typedef short bf16x8 __attribute__((ext_vector_type(8)));
typedef float f32x4 __attribute__((ext_vector_type(4)));

// dtype-agnostic float load: f32 flag chooses fp32 or bf16 interpretation
__device__ __forceinline__ float LD(const void* p, size_t i, int f32) {
    if (f32) return ((const float*)p)[i];
    unsigned u = ((const unsigned short*)p)[i];
    return __uint_as_float(u << 16);
}
__device__ __forceinline__ unsigned fkey(float f) {
    unsigned b = __float_as_uint(f);
    return (b & 0x80000000u) ? ~b : (b | 0x80000000u);
}
__device__ __forceinline__ float funkey(unsigned k) {
    unsigned b = (k & 0x80000000u) ? (k & 0x7fffffffu) : ~k;
    return __uint_as_float(b);
}
__device__ __forceinline__ unsigned short rnebf(float x) {
    unsigned u = __float_as_uint(x);
    return (unsigned short)((u + 0x7FFFu + ((u >> 16) & 1u)) >> 16);
}
__device__ __forceinline__ unsigned pk2(float lo, float hi) {
    return (unsigned)rnebf(lo) | ((unsigned)rnebf(hi) << 16);
}
__device__ __forceinline__ float plo(unsigned u) { return __uint_as_float(u << 16); }
__device__ __forceinline__ float phi(unsigned u) { return __uint_as_float(u & 0xFFFF0000u); }
__device__ __forceinline__ float wsum(float x) {
    x += __int_as_float(__builtin_amdgcn_update_dpp(0, __float_as_int(x), 0xB1, 0xF, 0xF, true));
    x += __int_as_float(__builtin_amdgcn_update_dpp(0, __float_as_int(x), 0x4E, 0xF, 0xF, true));
    x += __int_as_float(__builtin_amdgcn_update_dpp(0, __float_as_int(x), 0x141, 0xF, 0xF, true));
    x += __int_as_float(__builtin_amdgcn_update_dpp(0, __float_as_int(x), 0x140, 0xF, 0xF, true));
    x += __shfl_xor(x, 16, 64);
    x += __shfl_xor(x, 32, 64);
    return x;
}

// ---------------- dtype detection ------------------------------------------
__global__ void k_detect(const void* __restrict__ att_rc, int* __restrict__ flagp) {
    __shared__ int cnt;
    if (threadIdx.x == 0) cnt = 0;
    __syncthreads();
    const unsigned short* w = (const unsigned short*)att_rc;
    int c = 0;
    for (int i = threadIdx.x; i < 8192; i += 256) {
        unsigned e = (w[i] >> 7) & 0xFF;
        if (e >= 0xC0) c++;
    }
    atomicAdd(&cnt, c);
    __syncthreads();
    if (threadIdx.x == 0) *flagp = (cnt > 8) ? 1 : 0;
}

// ---------------- CSR build ------------------------------------------------
__global__ void k_count(const int* __restrict__ dst, int* __restrict__ cnt) {
    int i = blockIdx.x * blockDim.x + threadIdx.x;
    int stride = gridDim.x * blockDim.x;
    for (int e = i; e < N_EDGES; e += stride) atomicAdd(&cnt[dst[e]], 1);
}

__global__ void k_scan(const int* __restrict__ cnt, int* __restrict__ rowptr,
                       int* __restrict__ cursor) {
    __shared__ int ts[1024];
    int t = threadIdx.x;
    const int CH = 49;
    int b = t * CH, e = b + CH;
    if (b > N_NODES) b = N_NODES;
    if (e > N_NODES) e = N_NODES;
    int s = 0;
    for (int i = b; i < e; i++) s += cnt[i];
    ts[t] = s;
    __syncthreads();
    for (int off = 1; off < 1024; off <<= 1) {
        int v = (t >= off) ? ts[t - off] : 0;
        __syncthreads();
        ts[t] += v;
        __syncthreads();
    }
    int run = ts[t] - s;
    for (int i = b; i < e; i++) { rowptr[i] = run; cursor[i] = run; run += cnt[i]; }
    if (t == 1023) rowptr[N_NODES] = run;
}

__global__ void k_fill(const int* __restrict__ src, const int* __restrict__ dst,
                       const int* __restrict__ etype, const int* __restrict__ rid,
                       const void* __restrict__ att_rc, const void* __restrict__ att_rp,
                       int* __restrict__ cursor, int* __restrict__ src_p,
                       uint4* __restrict__ emeta, const int* __restrict__ flagp) {
    const int f32 = *flagp;
    int i = blockIdx.x * blockDim.x + threadIdx.x;
    int stride = gridDim.x * blockDim.x;
    for (int e = i; e < N_EDGES; e += stride) {
        int d = dst[e];
        int j = atomicAdd(&cursor[d], 1);
        src_p[j] = src[e];
        float rc0 = LD(att_rc, 2 * (size_t)e, f32), rc1 = LD(att_rc, 2 * (size_t)e + 1, f32);
        float rp0 = LD(att_rp, 3 * (size_t)e, f32), rp1 = LD(att_rp, 3 * (size_t)e + 1, f32),
              rp2 = LD(att_rp, 3 * (size_t)e + 2, f32);
        uint4 m;
        m.x = pk2(rc0, rc1);
        m.y = pk2(rp0, rp1);
        m.z = pk2(rp2, 0.f);
        m.w = (unsigned)(etype[e] | (rid[e] << 3));
        emeta[j] = m;
    }
}

// ---------------- initial feature MLP --------------------------------------
__global__ void k_init(const void* __restrict__ feat,
                       const void* __restrict__ W0, const void* __restrict__ b0,
                       const void* __restrict__ W1, const void* __restrict__ b1,
                       float* __restrict__ feats, const int* __restrict__ flagp) {
    const int f32 = *flagp;
    __shared__ float sf[64 * 12];
    __shared__ float sW0[IN_DIM * 64];
    __shared__ float sb0[64], sb1[64];
    __shared__ float sh[64 * 64];
    __shared__ float sW1[64 * 64];
    int tid = threadIdx.x, n0 = blockIdx.x * 64;
    for (int i = tid; i < IN_DIM * 64; i += 256) sW0[i] = LD(W0, i, f32);
    for (int i = tid; i < 64; i += 256) { sb0[i] = LD(b0, i, f32); sb1[i] = LD(b1, i, f32); }
    for (int i = tid; i < 64 * 64; i += 256) sW1[i] = LD(W1, i, f32);
    for (int i = tid; i < 64 * IN_DIM; i += 256) {
        int n = n0 + i / IN_DIM, c = i % IN_DIM;
        sf[(i / IN_DIM) * 12 + c] = (n < N_NODES) ? LD(feat, (size_t)n * IN_DIM + c, f32) : 0.f;
    }
    __syncthreads();
    int ng = tid / 16, cg = tid % 16;
    float acc[4][4];
    #pragma unroll
    for (int i = 0; i < 4; i++)
        #pragma unroll
        for (int j = 0; j < 4; j++) acc[i][j] = sb0[cg * 4 + j];
    #pragma unroll
    for (int k = 0; k < IN_DIM; k++)
        #pragma unroll
        for (int i = 0; i < 4; i++) {
            float a = sf[(ng * 4 + i) * 12 + k];
            #pragma unroll
            for (int j = 0; j < 4; j++) acc[i][j] += a * sW0[k * 64 + cg * 4 + j];
        }
    #pragma unroll
    for (int i = 0; i < 4; i++)
        #pragma unroll
        for (int j = 0; j < 4; j++) sh[(ng * 4 + i) * 64 + cg * 4 + j] = fmaxf(acc[i][j], 0.f);
    __syncthreads();
    float o[4][4];
    #pragma unroll
    for (int i = 0; i < 4; i++)
        #pragma unroll
        for (int j = 0; j < 4; j++) o[i][j] = sb1[cg * 4 + j];
    for (int k = 0; k < 64; k++) {
        float4 bv = *(const float4*)&sW1[k * 64 + cg * 4];
        #pragma unroll
        for (int i = 0; i < 4; i++) {
            float a = sh[(ng * 4 + i) * 64 + k];
            o[i][0] += a * bv.x; o[i][1] += a * bv.y;
            o[i][2] += a * bv.z; o[i][3] += a * bv.w;
        }
    }
    #pragma unroll
    for (int i = 0; i < 4; i++) {
        int n = n0 + ng * 4 + i;
        if (n < N_NODES) {
            float* r = feats + (size_t)n * F_TOT;
            #pragma unroll
            for (int j = 0; j < 4; j++) r[IN_DIM + cg * 4 + j] = o[i][j];
        }
    }
    for (int i = tid; i < 64 * IN_DIM; i += 256) {
        int n = n0 + i / IN_DIM, c = i % IN_DIM;
        if (n < N_NODES) feats[(size_t)n * F_TOT + c] = sf[(i / IN_DIM) * 12 + c];
    }
}

// ---------------- fused edge tables ----------------------------------------
__global__ void k_tables(const void* __restrict__ etype_emb, const void* __restrict__ rid_emb,
                         const void* __restrict__ rc_W, const void* __restrict__ rc_b,
                         const void* __restrict__ rp_W, const void* __restrict__ rp_b,
                         const void* __restrict__ W_fij, const void* __restrict__ egat_bias,
                         float* __restrict__ T, const int* __restrict__ flagp) {
    const int f32 = *flagp;
    int l = blockIdx.x;
    __shared__ float S[NT_ROWS * HID];
    __shared__ float W[HID * HO];
    for (int i = threadIdx.x; i < 7 * HID; i += 256) S[i] = LD(etype_emb, i, f32);
    for (int i = threadIdx.x; i < 31 * HID; i += 256) S[7 * HID + i] = LD(rid_emb, i, f32);
    for (int i = threadIdx.x; i < 2 * HID; i += 256) S[38 * HID + i] = LD(rc_W, i, f32);
    for (int i = threadIdx.x; i < 3 * HID; i += 256) S[40 * HID + i] = LD(rp_W, i, f32);
    for (int i = threadIdx.x; i < HID; i += 256)
        S[43 * HID + i] = LD(rc_b, i, f32) + LD(rp_b, i, f32);
    for (int i = threadIdx.x; i < HID * HO; i += 256)
        W[i] = LD(W_fij, (size_t)l * HID * HO + i, f32);
    __syncthreads();
    for (int idx = threadIdx.x; idx < NT_ROWS * HO; idx += 256) {
        int r = idx / HO, c = idx % HO;
        float acc = (r == 43) ? LD(egat_bias, l * HO + c, f32) : 0.f;
        for (int k = 0; k < HID; k++) acc += S[r * HID + k] * W[k * HO + c];
        T[(size_t)l * NT_ROWS * HO + idx] = acc;
    }
}

// ---------------- node GEMMs via MFMA -> packed bf16 gather buffers --------
// gsrc[n*128 + c*2 + 0] = pk(f_ni[n][c], f_ni[n][c+64])
// gsrc[n*128 + c*2 + 1] = pk(hw[n][c],   hw[n][c+64])
// gdst[n*64  + c]       = pk(f_nj[n][c], f_nj[n][c+64])
__global__ void __launch_bounds__(256) k_ngemm(
        const float* __restrict__ feats, int h_off,
        const void* __restrict__ W_ni, const void* __restrict__ W_nj,
        const void* __restrict__ W_node, int l,
        unsigned* __restrict__ gsrc, unsigned* __restrict__ gdst,
        const int* __restrict__ flagp) {
    const int f32 = *flagp;
    __shared__ unsigned short Xs[64 * 72];    // 9 KB, stride 72 (16B-aligned rows)
    __shared__ unsigned short Ws[384 * 72];   // 54 KB transposed: [m*128+c][k]
    int tid = threadIdx.x, n0 = blockIdx.x * 64;
    for (int i = tid; i < 64 * 64; i += 256) {
        int n = i >> 6, c = i & 63, gn = n0 + n;
        Xs[n * 72 + c] = rnebf((gn < N_NODES) ? feats[(size_t)gn * F_TOT + h_off + c] : 0.f);
    }
    for (int i = tid; i < 3 * 64 * 128; i += 256) {
        int m = i >> 13, r = i & 8191, k = r >> 7, c = r & 127;
        const void* W = (m == 0) ? W_ni : (m == 1) ? W_nj : W_node;
        Ws[(m * 128 + c) * 72 + k] = rnebf(LD(W, (size_t)l * 8192 + k * 128 + c, f32));
    }
    __syncthreads();
    int wid = tid >> 6, lane = tid & 63;
    int row0 = wid * 16, mrow = lane & 15, quad = lane >> 4;
    bf16x8 a0 = *(const bf16x8*)&Xs[(row0 + mrow) * 72 + quad * 8];
    bf16x8 a1 = *(const bf16x8*)&Xs[(row0 + mrow) * 72 + 32 + quad * 8];
    // m=0 (f_ni) and m=2 (hw) accumulators
    f32x4 accA[8], accB[8];
    #pragma unroll
    for (int j = 0; j < 8; j++) { accA[j] = (f32x4){0,0,0,0}; accB[j] = (f32x4){0,0,0,0}; }
    #pragma unroll
    for (int j = 0; j < 8; j++) {
        bf16x8 b0 = *(const bf16x8*)&Ws[(0 * 128 + j * 16 + mrow) * 72 + quad * 8];
        bf16x8 b1 = *(const bf16x8*)&Ws[(0 * 128 + j * 16 + mrow) * 72 + 32 + quad * 8];
        accA[j] = __builtin_amdgcn_mfma_f32_16x16x32_bf16(a0, b0, accA[j], 0, 0, 0);
        accA[j] = __builtin_amdgcn_mfma_f32_16x16x32_bf16(a1, b1, accA[j], 0, 0, 0);
        bf16x8 c0 = *(const bf16x8*)&Ws[(2 * 128 + j * 16 + mrow) * 72 + quad * 8];
        bf16x8 c1 = *(const bf16x8*)&Ws[(2 * 128 + j * 16 + mrow) * 72 + 32 + quad * 8];
        accB[j] = __builtin_amdgcn_mfma_f32_16x16x32_bf16(a0, c0, accB[j], 0, 0, 0);
        accB[j] = __builtin_amdgcn_mfma_f32_16x16x32_bf16(a1, c1, accB[j], 0, 0, 0);
    }
    #pragma unroll
    for (int j = 0; j < 4; j++) {
        int c = j * 16 + mrow;
        #pragma unroll
        for (int r = 0; r < 4; r++) {
            int gn = n0 + row0 + quad * 4 + r;
            if (gn < N_NODES) {
                uint2 v;
                v.x = pk2(accA[j][r], accA[j + 4][r]);
                v.y = pk2(accB[j][r], accB[j + 4][r]);
                *(uint2*)&gsrc[(size_t)gn * 128 + c * 2] = v;
            }
        }
    }
    // m=1 (f_nj -> gdst)
    f32x4 accC[8];
    #pragma unroll
    for (int j = 0; j < 8; j++) accC[j] = (f32x4){0,0,0,0};
    #pragma unroll
    for (int j = 0; j < 8; j++) {
        bf16x8 b0 = *(const bf16x8*)&Ws[(1 * 128 + j * 16 + mrow) * 72 + quad * 8];
        bf16x8 b1 = *(const bf16x8*)&Ws[(1 * 128 + j * 16 + mrow) * 72 + 32 + quad * 8];
        accC[j] = __builtin_amdgcn_mfma_f32_16x16x32_bf16(a0, b0, accC[j], 0, 0, 0);
        accC[j] = __builtin_amdgcn_mfma_f32_16x16x32_bf16(a1, b1, accC[j], 0, 0, 0);
    }
    #pragma unroll
    for (int j = 0; j < 4; j++) {
        int c = j * 16 + mrow;
        #pragma unroll
        for (int r = 0; r < 4; r++) {
            int gn = n0 + row0 + quad * 4 + r;
            if (gn < N_NODES)
                gdst[(size_t)gn * 64 + c] = pk2(accC[j][r], accC[j + 4][r]);
        }
    }
}

// ---------------- fused edge phase: logits + online softmax + aggregate ----
__global__ void __launch_bounds__(256) k_edge_fused(
        const float* __restrict__ T, const void* __restrict__ attn, int l,
        const unsigned* __restrict__ gsrc, const unsigned* __restrict__ gdst,
        const int* __restrict__ rowptr, const int* __restrict__ src_p,
        const uint4* __restrict__ emeta, float* __restrict__ h_att,
        const int* __restrict__ flagp) {
    const int f32 = *flagp;
    __shared__ float Ts[38 * HO];
    const float* Tl = T + (size_t)l * NT_ROWS * HO;
    for (int i4 = threadIdx.x; i4 < 38 * HO / 4; i4 += 256)
        ((float4*)Ts)[i4] = ((const float4*)Tl)[i4];
    int lane = threadIdx.x & 63;
    float C0[6], C1[6];
    #pragma unroll
    for (int r = 0; r < 6; r++) {
        C0[r] = Tl[(38 + r) * HO + lane];
        C1[r] = Tl[(38 + r) * HO + 64 + lane];
    }
    float AT0 = LD(attn, l * HO + lane, f32), AT1 = LD(attn, l * HO + 64 + lane, f32);
    __syncthreads();
    int d = blockIdx.x * 4 + (threadIdx.x >> 6);
    int jb = rowptr[d], je = rowptr[d + 1];
    unsigned gd = gdst[(size_t)d * 64 + lane];
    float nj0 = plo(gd), nj1 = phi(gd);
    float m0 = -INFINITY, l0 = 0.f, a0 = 0.f;
    float m1 = -INFINITY, l1 = 0.f, a1 = 0.f;
    int sn = 0; uint4 em = make_uint4(0, 0, 0, 0); uint2 g = make_uint2(0, 0);
    if (jb < je) {
        sn = src_p[jb]; em = emeta[jb];
        g = *(const uint2*)&gsrc[(size_t)sn * 128 + lane * 2];
    }
    for (int j = jb; j < je; j++) {
        unsigned tab = em.w;
        float rc0 = plo(em.x), rc1 = phi(em.x);
        float rp0 = plo(em.y), rp1 = phi(em.y), rp2 = plo(em.z);
        float ni0 = plo(g.x), ni1 = phi(g.x);
        float h0 = plo(g.y), h1 = phi(g.y);
        if (j + 1 < je) {
            sn = src_p[j + 1]; em = emeta[j + 1];
            g = *(const uint2*)&gsrc[(size_t)sn * 128 + lane * 2];
        }
        int et = tab & 7, ri = (int)(tab >> 3);
        float x0 = ni0 + nj0 + Ts[et * HO + lane] + Ts[(7 + ri) * HO + lane]
                 + rc0 * C0[0] + rc1 * C0[1] + rp0 * C0[2] + rp1 * C0[3]
                 + rp2 * C0[4] + C0[5];
        float x1 = ni1 + nj1 + Ts[et * HO + 64 + lane] + Ts[(7 + ri) * HO + 64 + lane]
                 + rc0 * C1[0] + rc1 * C1[1] + rp0 * C1[2] + rp1 * C1[3]
                 + rp2 * C1[4] + C1[5];
        x0 = (x0 > 0.f) ? x0 : NEG_SLOPE * x0;
        x1 = (x1 > 0.f) ? x1 : NEG_SLOPE * x1;
        float e0 = wsum(x0 * AT0), e1 = wsum(x1 * AT1);
        float nm0 = fmaxf(m0, e0), nm1 = fmaxf(m1, e1);
        float sc0 = __expf(m0 - nm0), sc1 = __expf(m1 - nm1);
        float w0 = __expf(e0 - nm0), w1 = __expf(e1 - nm1);
        l0 = l0 * sc0 + w0; a0 = a0 * sc0 + w0 * h0; m0 = nm0;
        l1 = l1 * sc1 + w1; a1 = a1 * sc1 + w1 * h1; m1 = nm1;
    }
    h_att[(size_t)d * HO + lane]      = a0 / (l0 + 1e-9f);
    h_att[(size_t)d * HO + 64 + lane] = a1 / (l1 + 1e-9f);
}

// ---------------- node MLP + residual via MFMA ------------------------------
__global__ void __launch_bounds__(256) k_mlp(
        const float* __restrict__ h_att,
        const void* __restrict__ Wm0, const void* __restrict__ bm0,
        const void* __restrict__ Wm1, const void* __restrict__ bm1, int l,
        float* __restrict__ feats, int prev_off, int out_off,
        const int* __restrict__ flagp) {
    const int f32 = *flagp;
    __shared__ unsigned short Xs[64 * 136];    // 17 KB; X then overwritten by Y (wave-local)
    __shared__ unsigned short W0T[128 * 136];  // 34 KB: [c][k]
    __shared__ unsigned short W1T[64 * 136];   // 17 KB: [c][k]
    __shared__ float sb0[HO], sb1[64];
    int tid = threadIdx.x, n0 = blockIdx.x * 64;
    for (int i = tid; i < 64 * 128; i += 256) {
        int n = i >> 7, c = i & 127, gn = n0 + n;
        Xs[n * 136 + c] = rnebf((gn < N_NODES) ? h_att[(size_t)gn * HO + c] : 0.f);
    }
    for (int i = tid; i < 128 * 128; i += 256) {
        int k = i >> 7, c = i & 127;
        W0T[c * 136 + k] = rnebf(LD(Wm0, (size_t)l * 16384 + k * 128 + c, f32));
    }
    for (int i = tid; i < 128 * 64; i += 256) {
        int k = i >> 6, c = i & 63;
        W1T[c * 136 + k] = rnebf(LD(Wm1, (size_t)l * 8192 + k * 64 + c, f32));
    }
    for (int i = tid; i < HO; i += 256) sb0[i] = LD(bm0, l * HO + i, f32);
    for (int i = tid; i < 64; i += 256) sb1[i] = LD(bm1, l * 64 + i, f32);
    __syncthreads();
    int wid = tid >> 6, lane = tid & 63;
    int row0 = wid * 16, mrow = lane & 15, quad = lane >> 4;
    // stage A: Y = relu(X @ W0 + b0)
    f32x4 acc[8];
    #pragma unroll
    for (int j = 0; j < 8; j++) {
        float b = sb0[j * 16 + mrow];
        acc[j] = (f32x4){b, b, b, b};
    }
    #pragma unroll
    for (int ks = 0; ks < 4; ks++) {
        bf16x8 a = *(const bf16x8*)&Xs[(row0 + mrow) * 136 + ks * 32 + quad * 8];
        #pragma unroll
        for (int j = 0; j < 8; j++) {
            bf16x8 b = *(const bf16x8*)&W0T[(j * 16 + mrow) * 136 + ks * 32 + quad * 8];
            acc[j] = __builtin_amdgcn_mfma_f32_16x16x32_bf16(a, b, acc[j], 0, 0, 0);
        }
    }
    // write Y back into Xs (wave-local stripe; data deps order the LDS ops)
    #pragma unroll
    for (int j = 0; j < 8; j++)
        #pragma unroll
        for (int r = 0; r < 4; r++)
            Xs[(row0 + quad * 4 + r) * 136 + j * 16 + mrow] = rnebf(fmaxf(acc[j][r], 0.f));
    // stage B: O = Y @ W1 + b1 + residual
    f32x4 o[4];
    #pragma unroll
    for (int j = 0; j < 4; j++) {
        float b = sb1[j * 16 + mrow];
        o[j] = (f32x4){b, b, b, b};
    }
    #pragma unroll
    for (int ks = 0; ks < 4; ks++) {
        bf16x8 a = *(const bf16x8*)&Xs[(row0 + mrow) * 136 + ks * 32 + quad * 8];
        #pragma unroll
        for (int j = 0; j < 4; j++) {
            bf16x8 b = *(const bf16x8*)&W1T[(j * 16 + mrow) * 136 + ks * 32 + quad * 8];
            o[j] = __builtin_amdgcn_mfma_f32_16x16x32_bf16(a, b, o[j], 0, 0, 0);
        }
    }
    #pragma unroll
    for (int j = 0; j < 4; j++) {
        int c = j * 16 + mrow;
        #pragma unroll
        for (int r = 0; r < 4; r++) {
            int gn = n0 + row0 + quad * 4 + r;
            if (gn < N_NODES) {
                float* rw = feats + (size_t)gn * F_TOT;
                rw[out_off + c] = o[j][r] + rw[prev_off + c];
            }
        }
    }
}

// ---------------- graph max pool -------------------------------------------
__global__ void k_pool(const float* __restrict__ feats, unsigned* __restrict__ gmax) {
    int g = blockIdx.x;
    int chunk = blockIdx.y;
    int t = threadIdx.x;
    const int CS = (NPG + 15) / 16;
    int nb = chunk * CS;
    int ne = (nb + CS < NPG) ? nb + CS : NPG;
    float m0 = -INFINITY, m1 = -INFINITY;
    for (int n = nb; n < ne; n++) {
        const float* row = feats + (size_t)(g * NPG + n) * F_TOT;
        m0 = fmaxf(m0, row[t]);
        if (t + 256 < F_TOT) m1 = fmaxf(m1, row[t + 256]);
    }
    atomicMax(&gmax[g * F_TOT + t], fkey(m0));
    if (t + 256 < F_TOT) atomicMax(&gmax[g * F_TOT + t + 256], fkey(m1));
}

// ---------------- output write ---------------------------------------------
__global__ void k_out(const float* __restrict__ feats, const unsigned* __restrict__ gmax,
                      void* __restrict__ out, const int* __restrict__ flagp) {
    const int f32 = *flagp;
    size_t total = (size_t)B_GRAPHS * NPG * OUT_C;
    size_t stride = (size_t)gridDim.x * blockDim.x;
    for (size_t i = (size_t)blockIdx.x * blockDim.x + threadIdx.x; i < total; i += stride) {
        int c = (int)(i % OUT_C);
        size_t gn = i / OUT_C;
        int g = (int)(gn / NPG);
        float v = (c < F_TOT) ? feats[gn * F_TOT + c] : funkey(gmax[g * F_TOT + (c - F_TOT)]);
        if (f32) ((float*)out)[i] = v;
        else ((__hip_bfloat16*)out)[i] = __float2bfloat16(v);
    }
}

extern "C" void kernel_launch(void* const* d_in, const int* in_sizes, int n_in,
                              void* d_out, int out_size, void* d_ws, size_t ws_size,
                              hipStream_t stream) {
    const void* feat      = d_in[0];
    const void* att_rc    = d_in[1];
    const void* att_rp    = d_in[2];
    const void* etype_emb = d_in[3];
    const void* rid_emb   = d_in[4];
    const void* rc_W      = d_in[5];
    const void* rc_b      = d_in[6];
    const void* rp_W      = d_in[7];
    const void* rp_b      = d_in[8];
    const void* fe_W0     = d_in[9];
    const void* fe_b0     = d_in[10];
    const void* fe_W1     = d_in[11];
    const void* fe_b1     = d_in[12];
    const void* W_ni      = d_in[13];
    const void* W_nj      = d_in[14];
    const void* W_fij     = d_in[15];
    const void* W_node    = d_in[16];
    const void* attn      = d_in[17];
    const void* egat_bias = d_in[18];
    const void* Wm0       = d_in[19];
    const void* bm0       = d_in[20];
    const void* Wm1       = d_in[21];
    const void* bm1       = d_in[22];
    const int* src   = (const int*)d_in[23];
    const int* dst   = (const int*)d_in[24];
    const int* etype = (const int*)d_in[25];
    const int* rid   = (const int*)d_in[26];

    char* p = (char*)d_ws;
    auto alloc = [&](size_t bytes) {
        char* r = p;
        p += (bytes + 255) & ~(size_t)255;
        return r;
    };
    float*    feats  = (float*)alloc((size_t)N_NODES * F_TOT * 4);    // 53.2 MB
    unsigned* gsrc   = (unsigned*)alloc((size_t)N_NODES * HO * 4);    // 25.6 MB
    unsigned* gdst   = (unsigned*)alloc((size_t)N_NODES * 64 * 4);    // 12.8 MB
    float*    h_att  = (float*)alloc((size_t)N_NODES * HO * 4);       // 25.6 MB
    float*    T      = (float*)alloc((size_t)3 * NT_ROWS * HO * 4);
    unsigned* gmax   = (unsigned*)alloc((size_t)B_GRAPHS * F_TOT * 4);
    int*      flagp  = (int*)alloc(256);
    int*      rowptr = (int*)alloc((size_t)(N_NODES + 1) * 4);
    int*      cursor = (int*)alloc((size_t)N_NODES * 4);
    int*      cnt    = (int*)alloc((size_t)N_NODES * 4);
    int*      src_p  = (int*)alloc((size_t)N_EDGES * 4);
    uint4*    emeta  = (uint4*)alloc((size_t)N_EDGES * 16);

    k_detect<<<1, 256, 0, stream>>>(att_rc, flagp);
    hipMemsetAsync(cnt, 0, (size_t)N_NODES * 4, stream);
    hipMemsetAsync(gmax, 0, (size_t)B_GRAPHS * F_TOT * 4, stream);
    k_count<<<512, 256, 0, stream>>>(dst, cnt);
    k_scan<<<1, 1024, 0, stream>>>(cnt, rowptr, cursor);
    k_fill<<<1024, 256, 0, stream>>>(src, dst, etype, rid, att_rc, att_rp,
                                     cursor, src_p, emeta, flagp);
    k_init<<<(N_NODES + 63) / 64, 256, 0, stream>>>(feat, fe_W0, fe_b0, fe_W1, fe_b1,
                                                    feats, flagp);
    k_tables<<<3, 256, 0, stream>>>(etype_emb, rid_emb, rc_W, rc_b, rp_W, rp_b,
                                    W_fij, egat_bias, T, flagp);
    for (int l = 0; l < 3; l++) {
        int h_off = IN_DIM + l * HID;
        int out_off = IN_DIM + (l + 1) * HID;
        k_ngemm<<<(N_NODES + 63) / 64, 256, 0, stream>>>(feats, h_off, W_ni, W_nj, W_node, l,
                                                         gsrc, gdst, flagp);
        k_edge_fused<<<N_NODES / 4, 256, 0, stream>>>(T, attn, l, gsrc, gdst,
                                                      rowptr, src_p, emeta, h_att, flagp);
        k_mlp<<<(N_NODES + 63) / 64, 256, 0, stream>>>(h_att, Wm0, bm0, Wm1, bm1, l,
                                                       feats, h_off, out_off, flagp);
    }
    k_pool<<<dim3(B_GRAPHS, 16), 256, 0, stream>>>(feats, gmax);
    k_out<<<4096, 256, 0, stream>>>(feats, gmax, d_out, flagp);
}

// Round 6
// 1261.754 us; speedup vs baseline: 2.8322x; 1.0706x over previous
//
#include <hip/hip_runtime.h>
#include <hip/hip_bf16.h>
#include <math.h>

#define N_NODES 50000
#define N_EDGES 500000
#define B_GRAPHS 8
#define NPG 6250
#define HID 64
#define HO 128          // HEADS*HID
#define IN_DIM 10
#define F_TOT 266       // IN_DIM + 4*HID
#define OUT_C 532       // 2*F_TOT
#define NEG_SLOPE 0.2f
#define NT_ROWS 44      // 7 etype + 31 rid + 2 rc + 3 rp + 1 const

typedef short bf16x8 __attribute__((ext_vector_type(8)));
typedef float f32x4 __attribute__((ext_vector_type(4)));

// dtype-agnostic float load: f32 flag chooses fp32 or bf16 interpretation
__device__ __forceinline__ float LD(const void* p, size_t i, int f32) {
    if (f32) return ((const float*)p)[i];
    unsigned u = ((const unsigned short*)p)[i];
    return __uint_as_float(u << 16);
}
__device__ __forceinline__ unsigned fkey(float f) {
    unsigned b = __float_as_uint(f);
    return (b & 0x80000000u) ? ~b : (b | 0x80000000u);
}
__device__ __forceinline__ float funkey(unsigned k) {
    unsigned b = (k & 0x80000000u) ? (k & 0x7fffffffu) : ~k;
    return __uint_as_float(b);
}
__device__ __forceinline__ unsigned short rnebf(float x) {
    unsigned u = __float_as_uint(x);
    return (unsigned short)((u + 0x7FFFu + ((u >> 16) & 1u)) >> 16);
}
__device__ __forceinline__ unsigned pk2(float lo, float hi) {
    return (unsigned)rnebf(lo) | ((unsigned)rnebf(hi) << 16);
}
__device__ __forceinline__ float plo(unsigned u) { return __uint_as_float(u << 16); }
__device__ __forceinline__ float phi(unsigned u) { return __uint_as_float(u & 0xFFFF0000u); }
__device__ __forceinline__ float wsum(float x) {
    x += __int_as_float(__builtin_amdgcn_update_dpp(0, __float_as_int(x), 0xB1, 0xF, 0xF, true));
    x += __int_as_float(__builtin_amdgcn_update_dpp(0, __float_as_int(x), 0x4E, 0xF, 0xF, true));
    x += __int_as_float(__builtin_amdgcn_update_dpp(0, __float_as_int(x), 0x141, 0xF, 0xF, true));
    x += __int_as_float(__builtin_amdgcn_update_dpp(0, __float_as_int(x), 0x140, 0xF, 0xF, true));
    x += __shfl_xor(x, 16, 64);
    x += __shfl_xor(x, 32, 64);
    return x;
}

// ---------------- dtype detection ------------------------------------------
__global__ void k_detect(const void* __restrict__ att_rc, int* __restrict__ flagp) {
    __shared__ int cnt;
    if (threadIdx.x == 0) cnt = 0;
    __syncthreads();
    const unsigned short* w = (const unsigned short*)att_rc;
    int c = 0;
    for (int i = threadIdx.x; i < 8192; i += 256) {
        unsigned e = (w[i] >> 7) & 0xFF;
        if (e >= 0xC0) c++;
    }
    atomicAdd(&cnt, c);
    __syncthreads();
    if (threadIdx.x == 0) *flagp = (cnt > 8) ? 1 : 0;
}

// ---------------- CSR build ------------------------------------------------
__global__ void k_count(const int* __restrict__ dst, int* __restrict__ cnt) {
    int i = blockIdx.x * blockDim.x + threadIdx.x;
    int stride = gridDim.x * blockDim.x;
    for (int e = i; e < N_EDGES; e += stride) atomicAdd(&cnt[dst[e]], 1);
}

__global__ void k_scan(const int* __restrict__ cnt, int* __restrict__ rowptr,
                       int* __restrict__ cursor) {
    __shared__ int ts[1024];
    int t = threadIdx.x;
    const int CH = 49;
    int b = t * CH, e = b + CH;
    if (b > N_NODES) b = N_NODES;
    if (e > N_NODES) e = N_NODES;
    int s = 0;
    for (int i = b; i < e; i++) s += cnt[i];
    ts[t] = s;
    __syncthreads();
    for (int off = 1; off < 1024; off <<= 1) {
        int v = (t >= off) ? ts[t - off] : 0;
        __syncthreads();
        ts[t] += v;
        __syncthreads();
    }
    int run = ts[t] - s;
    for (int i = b; i < e; i++) { rowptr[i] = run; cursor[i] = run; run += cnt[i]; }
    if (t == 1023) rowptr[N_NODES] = run;
}

// emeta.w = etype | rid<<3 | src<<8   (src < 65536)
__global__ void k_fill(const int* __restrict__ src, const int* __restrict__ dst,
                       const int* __restrict__ etype, const int* __restrict__ rid,
                       const void* __restrict__ att_rc, const void* __restrict__ att_rp,
                       int* __restrict__ cursor, uint4* __restrict__ emeta,
                       const int* __restrict__ flagp) {
    const int f32 = *flagp;
    int i = blockIdx.x * blockDim.x + threadIdx.x;
    int stride = gridDim.x * blockDim.x;
    for (int e = i; e < N_EDGES; e += stride) {
        int d = dst[e];
        int j = atomicAdd(&cursor[d], 1);
        float rc0 = LD(att_rc, 2 * (size_t)e, f32), rc1 = LD(att_rc, 2 * (size_t)e + 1, f32);
        float rp0 = LD(att_rp, 3 * (size_t)e, f32), rp1 = LD(att_rp, 3 * (size_t)e + 1, f32),
              rp2 = LD(att_rp, 3 * (size_t)e + 2, f32);
        uint4 m;
        m.x = pk2(rc0, rc1);
        m.y = pk2(rp0, rp1);
        m.z = pk2(rp2, 0.f);
        m.w = (unsigned)(etype[e] | (rid[e] << 3) | ((unsigned)src[e] << 8));
        emeta[j] = m;
    }
}

// ---------------- initial feature MLP --------------------------------------
__global__ void k_init(const void* __restrict__ feat,
                       const void* __restrict__ W0, const void* __restrict__ b0,
                       const void* __restrict__ W1, const void* __restrict__ b1,
                       float* __restrict__ feats, const int* __restrict__ flagp) {
    const int f32 = *flagp;
    __shared__ float sf[64 * 12];
    __shared__ float sW0[IN_DIM * 64];
    __shared__ float sb0[64], sb1[64];
    __shared__ float sh[64 * 64];
    __shared__ float sW1[64 * 64];
    int tid = threadIdx.x, n0 = blockIdx.x * 64;
    for (int i = tid; i < IN_DIM * 64; i += 256) sW0[i] = LD(W0, i, f32);
    for (int i = tid; i < 64; i += 256) { sb0[i] = LD(b0, i, f32); sb1[i] = LD(b1, i, f32); }
    for (int i = tid; i < 64 * 64; i += 256) sW1[i] = LD(W1, i, f32);
    for (int i = tid; i < 64 * IN_DIM; i += 256) {
        int n = n0 + i / IN_DIM, c = i % IN_DIM;
        sf[(i / IN_DIM) * 12 + c] = (n < N_NODES) ? LD(feat, (size_t)n * IN_DIM + c, f32) : 0.f;
    }
    __syncthreads();
    int ng = tid / 16, cg = tid % 16;
    float acc[4][4];
    #pragma unroll
    for (int i = 0; i < 4; i++)
        #pragma unroll
        for (int j = 0; j < 4; j++) acc[i][j] = sb0[cg * 4 + j];
    #pragma unroll
    for (int k = 0; k < IN_DIM; k++)
        #pragma unroll
        for (int i = 0; i < 4; i++) {
            float a = sf[(ng * 4 + i) * 12 + k];
            #pragma unroll
            for (int j = 0; j < 4; j++) acc[i][j] += a * sW0[k * 64 + cg * 4 + j];
        }
    #pragma unroll
    for (int i = 0; i < 4; i++)
        #pragma unroll
        for (int j = 0; j < 4; j++) sh[(ng * 4 + i) * 64 + cg * 4 + j] = fmaxf(acc[i][j], 0.f);
    __syncthreads();
    float o[4][4];
    #pragma unroll
    for (int i = 0; i < 4; i++)
        #pragma unroll
        for (int j = 0; j < 4; j++) o[i][j] = sb1[cg * 4 + j];
    for (int k = 0; k < 64; k++) {
        float4 bv = *(const float4*)&sW1[k * 64 + cg * 4];
        #pragma unroll
        for (int i = 0; i < 4; i++) {
            float a = sh[(ng * 4 + i) * 64 + k];
            o[i][0] += a * bv.x; o[i][1] += a * bv.y;
            o[i][2] += a * bv.z; o[i][3] += a * bv.w;
        }
    }
    #pragma unroll
    for (int i = 0; i < 4; i++) {
        int n = n0 + ng * 4 + i;
        if (n < N_NODES) {
            float* r = feats + (size_t)n * F_TOT;
            #pragma unroll
            for (int j = 0; j < 4; j++) r[IN_DIM + cg * 4 + j] = o[i][j];
        }
    }
    for (int i = tid; i < 64 * IN_DIM; i += 256) {
        int n = n0 + i / IN_DIM, c = i % IN_DIM;
        if (n < N_NODES) feats[(size_t)n * F_TOT + c] = sf[(i / IN_DIM) * 12 + c];
    }
}

// ---------------- fused edge tables ----------------------------------------
__global__ void k_tables(const void* __restrict__ etype_emb, const void* __restrict__ rid_emb,
                         const void* __restrict__ rc_W, const void* __restrict__ rc_b,
                         const void* __restrict__ rp_W, const void* __restrict__ rp_b,
                         const void* __restrict__ W_fij, const void* __restrict__ egat_bias,
                         float* __restrict__ T, const int* __restrict__ flagp) {
    const int f32 = *flagp;
    int l = blockIdx.x;
    __shared__ float S[NT_ROWS * HID];
    __shared__ float W[HID * HO];
    for (int i = threadIdx.x; i < 7 * HID; i += 256) S[i] = LD(etype_emb, i, f32);
    for (int i = threadIdx.x; i < 31 * HID; i += 256) S[7 * HID + i] = LD(rid_emb, i, f32);
    for (int i = threadIdx.x; i < 2 * HID; i += 256) S[38 * HID + i] = LD(rc_W, i, f32);
    for (int i = threadIdx.x; i < 3 * HID; i += 256) S[40 * HID + i] = LD(rp_W, i, f32);
    for (int i = threadIdx.x; i < HID; i += 256)
        S[43 * HID + i] = LD(rc_b, i, f32) + LD(rp_b, i, f32);
    for (int i = threadIdx.x; i < HID * HO; i += 256)
        W[i] = LD(W_fij, (size_t)l * HID * HO + i, f32);
    __syncthreads();
    for (int idx = threadIdx.x; idx < NT_ROWS * HO; idx += 256) {
        int r = idx / HO, c = idx % HO;
        float acc = (r == 43) ? LD(egat_bias, l * HO + c, f32) : 0.f;
        for (int k = 0; k < HID; k++) acc += S[r * HID + k] * W[k * HO + c];
        T[(size_t)l * NT_ROWS * HO + idx] = acc;
    }
}

// ---------------- node GEMMs via MFMA -> packed bf16 gather buffers --------
__global__ void __launch_bounds__(256) k_ngemm(
        const float* __restrict__ feats, int h_off,
        const void* __restrict__ W_ni, const void* __restrict__ W_nj,
        const void* __restrict__ W_node, int l,
        unsigned* __restrict__ gsrc, unsigned* __restrict__ gdst,
        const int* __restrict__ flagp) {
    const int f32 = *flagp;
    __shared__ unsigned short Xs[64 * 72];
    __shared__ unsigned short Ws[384 * 72];
    int tid = threadIdx.x, n0 = blockIdx.x * 64;
    for (int i = tid; i < 64 * 64; i += 256) {
        int n = i >> 6, c = i & 63, gn = n0 + n;
        Xs[n * 72 + c] = rnebf((gn < N_NODES) ? feats[(size_t)gn * F_TOT + h_off + c] : 0.f);
    }
    for (int i = tid; i < 3 * 64 * 128; i += 256) {
        int m = i >> 13, r = i & 8191, k = r >> 7, c = r & 127;
        const void* W = (m == 0) ? W_ni : (m == 1) ? W_nj : W_node;
        Ws[(m * 128 + c) * 72 + k] = rnebf(LD(W, (size_t)l * 8192 + k * 128 + c, f32));
    }
    __syncthreads();
    int wid = tid >> 6, lane = tid & 63;
    int row0 = wid * 16, mrow = lane & 15, quad = lane >> 4;
    bf16x8 a0 = *(const bf16x8*)&Xs[(row0 + mrow) * 72 + quad * 8];
    bf16x8 a1 = *(const bf16x8*)&Xs[(row0 + mrow) * 72 + 32 + quad * 8];
    f32x4 accA[8], accB[8];
    #pragma unroll
    for (int j = 0; j < 8; j++) { accA[j] = (f32x4){0,0,0,0}; accB[j] = (f32x4){0,0,0,0}; }
    #pragma unroll
    for (int j = 0; j < 8; j++) {
        bf16x8 b0 = *(const bf16x8*)&Ws[(0 * 128 + j * 16 + mrow) * 72 + quad * 8];
        bf16x8 b1 = *(const bf16x8*)&Ws[(0 * 128 + j * 16 + mrow) * 72 + 32 + quad * 8];
        accA[j] = __builtin_amdgcn_mfma_f32_16x16x32_bf16(a0, b0, accA[j], 0, 0, 0);
        accA[j] = __builtin_amdgcn_mfma_f32_16x16x32_bf16(a1, b1, accA[j], 0, 0, 0);
        bf16x8 c0 = *(const bf16x8*)&Ws[(2 * 128 + j * 16 + mrow) * 72 + quad * 8];
        bf16x8 c1 = *(const bf16x8*)&Ws[(2 * 128 + j * 16 + mrow) * 72 + 32 + quad * 8];
        accB[j] = __builtin_amdgcn_mfma_f32_16x16x32_bf16(a0, c0, accB[j], 0, 0, 0);
        accB[j] = __builtin_amdgcn_mfma_f32_16x16x32_bf16(a1, c1, accB[j], 0, 0, 0);
    }
    #pragma unroll
    for (int j = 0; j < 4; j++) {
        int c = j * 16 + mrow;
        #pragma unroll
        for (int r = 0; r < 4; r++) {
            int gn = n0 + row0 + quad * 4 + r;
            if (gn < N_NODES) {
                uint2 v;
                v.x = pk2(accA[j][r], accA[j + 4][r]);
                v.y = pk2(accB[j][r], accB[j + 4][r]);
                *(uint2*)&gsrc[(size_t)gn * 128 + c * 2] = v;
            }
        }
    }
    f32x4 accC[8];
    #pragma unroll
    for (int j = 0; j < 8; j++) accC[j] = (f32x4){0,0,0,0};
    #pragma unroll
    for (int j = 0; j < 8; j++) {
        bf16x8 b0 = *(const bf16x8*)&Ws[(1 * 128 + j * 16 + mrow) * 72 + quad * 8];
        bf16x8 b1 = *(const bf16x8*)&Ws[(1 * 128 + j * 16 + mrow) * 72 + 32 + quad * 8];
        accC[j] = __builtin_amdgcn_mfma_f32_16x16x32_bf16(a0, b0, accC[j], 0, 0, 0);
        accC[j] = __builtin_amdgcn_mfma_f32_16x16x32_bf16(a1, b1, accC[j], 0, 0, 0);
    }
    #pragma unroll
    for (int j = 0; j < 4; j++) {
        int c = j * 16 + mrow;
        #pragma unroll
        for (int r = 0; r < 4; r++) {
            int gn = n0 + row0 + quad * 4 + r;
            if (gn < N_NODES)
                gdst[(size_t)gn * 64 + c] = pk2(accC[j][r], accC[j + 4][r]);
        }
    }
}

// ---------------- fused edge phase: logits + online softmax + aggregate ----
__global__ void __launch_bounds__(256) k_edge_fused(
        const float* __restrict__ T, const void* __restrict__ attn, int l,
        const unsigned* __restrict__ gsrc, const unsigned* __restrict__ gdst,
        const int* __restrict__ rowptr, const uint4* __restrict__ emeta,
        float* __restrict__ h_att, const int* __restrict__ flagp) {
    const int f32 = *flagp;
    __shared__ float Ts[38 * HO];
    const float* Tl = T + (size_t)l * NT_ROWS * HO;
    for (int i4 = threadIdx.x; i4 < 38 * HO / 4; i4 += 256)
        ((float4*)Ts)[i4] = ((const float4*)Tl)[i4];
    int lane = threadIdx.x & 63;
    float C0[6], C1[6];
    #pragma unroll
    for (int r = 0; r < 6; r++) {
        C0[r] = Tl[(38 + r) * HO + lane];
        C1[r] = Tl[(38 + r) * HO + 64 + lane];
    }
    float AT0 = LD(attn, l * HO + lane, f32), AT1 = LD(attn, l * HO + 64 + lane, f32);
    __syncthreads();
    int d = blockIdx.x * 4 + (threadIdx.x >> 6);
    int jb = rowptr[d], je = rowptr[d + 1];
    unsigned gd = gdst[(size_t)d * 64 + lane];
    float nj0 = plo(gd), nj1 = phi(gd);
    float m0 = -INFINITY, l0 = 0.f, a0 = 0.f;
    float m1 = -INFINITY, l1 = 0.f, a1 = 0.f;

    // logits from one edge's (em, g): returns e0/e1 (wave-reduced) and h0/h1
    auto logits = [&](const uint4& em, const uint2& g,
                      float& e0, float& e1, float& h0, float& h1) {
        unsigned w = em.w;
        int et = (int)(w & 7u), ri = (int)((w >> 3) & 31u);
        float rc0 = plo(em.x), rc1 = phi(em.x);
        float rp0 = plo(em.y), rp1 = phi(em.y), rp2 = plo(em.z);
        float ni0 = plo(g.x), ni1 = phi(g.x);
        h0 = plo(g.y); h1 = phi(g.y);
        float x0 = ni0 + nj0 + Ts[et * HO + lane] + Ts[(7 + ri) * HO + lane]
                 + rc0 * C0[0] + rc1 * C0[1] + rp0 * C0[2] + rp1 * C0[3]
                 + rp2 * C0[4] + C0[5];
        float x1 = ni1 + nj1 + Ts[et * HO + 64 + lane] + Ts[(7 + ri) * HO + 64 + lane]
                 + rc0 * C1[0] + rc1 * C1[1] + rp0 * C1[2] + rp1 * C1[3]
                 + rp2 * C1[4] + C1[5];
        x0 = (x0 > 0.f) ? x0 : NEG_SLOPE * x0;
        x1 = (x1 > 0.f) ? x1 : NEG_SLOPE * x1;
        e0 = wsum(x0 * AT0);
        e1 = wsum(x1 * AT1);
    };
    auto update = [&](float e0, float e1, float h0, float h1) {
        float nm0 = fmaxf(m0, e0), nm1 = fmaxf(m1, e1);
        float sc0 = __expf(m0 - nm0), sc1 = __expf(m1 - nm1);
        float w0 = __expf(e0 - nm0), w1 = __expf(e1 - nm1);
        l0 = l0 * sc0 + w0; a0 = a0 * sc0 + w0 * h0; m0 = nm0;
        l1 = l1 * sc1 + w1; a1 = a1 * sc1 + w1 * h1; m1 = nm1;
    };
    auto fetch = [&](int j, uint4& em, uint2& g) {
        em = emeta[j];
        g = *(const uint2*)&gsrc[(size_t)(em.w >> 8) * 128 + lane * 2];
    };

    uint4 emA = make_uint4(0,0,0,0), emB = make_uint4(0,0,0,0);
    uint2 gA = make_uint2(0,0), gB = make_uint2(0,0);
    int j = jb;
    if (j < je)     fetch(j, emA, gA);
    if (j + 1 < je) fetch(j + 1, emB, gB);
    while (j + 2 <= je) {
        float e0a, e1a, h0a, h1a, e0b, e1b, h0b, h1b;
        logits(emA, gA, e0a, e1a, h0a, h1a);   // independent wsum chains
        logits(emB, gB, e0b, e1b, h0b, h1b);
        if (j + 2 < je) fetch(j + 2, emA, gA);
        if (j + 3 < je) fetch(j + 3, emB, gB);
        update(e0a, e1a, h0a, h1a);
        update(e0b, e1b, h0b, h1b);
        j += 2;
    }
    if (j < je) {
        float e0, e1, h0, h1;
        logits(emA, gA, e0, e1, h0, h1);
        update(e0, e1, h0, h1);
    }
    h_att[(size_t)d * HO + lane]      = a0 / (l0 + 1e-9f);
    h_att[(size_t)d * HO + 64 + lane] = a1 / (l1 + 1e-9f);
}

// ---------------- node MLP + residual via MFMA ------------------------------
__global__ void __launch_bounds__(256) k_mlp(
        const float* __restrict__ h_att,
        const void* __restrict__ Wm0, const void* __restrict__ bm0,
        const void* __restrict__ Wm1, const void* __restrict__ bm1, int l,
        float* __restrict__ feats, int prev_off, int out_off,
        const int* __restrict__ flagp) {
    const int f32 = *flagp;
    __shared__ unsigned short Xs[64 * 136];
    __shared__ unsigned short W0T[128 * 136];
    __shared__ unsigned short W1T[64 * 136];
    __shared__ float sb0[HO], sb1[64];
    int tid = threadIdx.x, n0 = blockIdx.x * 64;
    for (int i = tid; i < 64 * 128; i += 256) {
        int n = i >> 7, c = i & 127, gn = n0 + n;
        Xs[n * 136 + c] = rnebf((gn < N_NODES) ? h_att[(size_t)gn * HO + c] : 0.f);
    }
    for (int i = tid; i < 128 * 128; i += 256) {
        int k = i >> 7, c = i & 127;
        W0T[c * 136 + k] = rnebf(LD(Wm0, (size_t)l * 16384 + k * 128 + c, f32));
    }
    for (int i = tid; i < 128 * 64; i += 256) {
        int k = i >> 6, c = i & 63;
        W1T[c * 136 + k] = rnebf(LD(Wm1, (size_t)l * 8192 + k * 64 + c, f32));
    }
    for (int i = tid; i < HO; i += 256) sb0[i] = LD(bm0, l * HO + i, f32);
    for (int i = tid; i < 64; i += 256) sb1[i] = LD(bm1, l * 64 + i, f32);
    __syncthreads();
    int wid = tid >> 6, lane = tid & 63;
    int row0 = wid * 16, mrow = lane & 15, quad = lane >> 4;
    f32x4 acc[8];
    #pragma unroll
    for (int j = 0; j < 8; j++) {
        float b = sb0[j * 16 + mrow];
        acc[j] = (f32x4){b, b, b, b};
    }
    #pragma unroll
    for (int ks = 0; ks < 4; ks++) {
        bf16x8 a = *(const bf16x8*)&Xs[(row0 + mrow) * 136 + ks * 32 + quad * 8];
        #pragma unroll
        for (int j = 0; j < 8; j++) {
            bf16x8 b = *(const bf16x8*)&W0T[(j * 16 + mrow) * 136 + ks * 32 + quad * 8];
            acc[j] = __builtin_amdgcn_mfma_f32_16x16x32_bf16(a, b, acc[j], 0, 0, 0);
        }
    }
    #pragma unroll
    for (int j = 0; j < 8; j++)
        #pragma unroll
        for (int r = 0; r < 4; r++)
            Xs[(row0 + quad * 4 + r) * 136 + j * 16 + mrow] = rnebf(fmaxf(acc[j][r], 0.f));
    f32x4 o[4];
    #pragma unroll
    for (int j = 0; j < 4; j++) {
        float b = sb1[j * 16 + mrow];
        o[j] = (f32x4){b, b, b, b};
    }
    #pragma unroll
    for (int ks = 0; ks < 4; ks++) {
        bf16x8 a = *(const bf16x8*)&Xs[(row0 + mrow) * 136 + ks * 32 + quad * 8];
        #pragma unroll
        for (int j = 0; j < 4; j++) {
            bf16x8 b = *(const bf16x8*)&W1T[(j * 16 + mrow) * 136 + ks * 32 + quad * 8];
            o[j] = __builtin_amdgcn_mfma_f32_16x16x32_bf16(a, b, o[j], 0, 0, 0);
        }
    }
    #pragma unroll
    for (int j = 0; j < 4; j++) {
        int c = j * 16 + mrow;
        #pragma unroll
        for (int r = 0; r < 4; r++) {
            int gn = n0 + row0 + quad * 4 + r;
            if (gn < N_NODES) {
                float* rw = feats + (size_t)gn * F_TOT;
                rw[out_off + c] = o[j][r] + rw[prev_off + c];
            }
        }
    }
}

// ---------------- graph max pool (1024 blocks) ------------------------------
__global__ void k_pool(const float* __restrict__ feats, unsigned* __restrict__ gmax) {
    int g = blockIdx.x;
    int chunk = blockIdx.y;
    int t = threadIdx.x;
    const int CS = 49;   // 128 chunks x 49 >= 6250
    int nb = chunk * CS;
    int ne = (nb + CS < NPG) ? nb + CS : NPG;
    float m0 = -INFINITY, m1 = -INFINITY;
    for (int n = nb; n < ne; n++) {
        const float* row = feats + (size_t)(g * NPG + n) * F_TOT;
        m0 = fmaxf(m0, row[t]);
        if (t + 256 < F_TOT) m1 = fmaxf(m1, row[t + 256]);
    }
    atomicMax(&gmax[g * F_TOT + t], fkey(m0));
    if (t + 256 < F_TOT) atomicMax(&gmax[g * F_TOT + t + 256], fkey(m1));
}

// ---------------- output write: wave per row --------------------------------
__global__ void k_out(const float* __restrict__ feats, const unsigned* __restrict__ gmax,
                      void* __restrict__ out, const int* __restrict__ flagp) {
    const int f32 = *flagp;
    int lane = threadIdx.x & 63;
    int wave = (blockIdx.x * blockDim.x + threadIdx.x) >> 6;
    int nw = (gridDim.x * blockDim.x) >> 6;
    for (int row = wave; row < B_GRAPHS * NPG; row += nw) {
        int g = row / NPG;
        const float* fr = feats + (size_t)row * F_TOT;
        const unsigned* gr = gmax + g * F_TOT;
        if (f32) {
            float* o = (float*)out + (size_t)row * OUT_C;
            for (int c = lane; c < OUT_C; c += 64)
                o[c] = (c < F_TOT) ? fr[c] : funkey(gr[c - F_TOT]);
        } else {
            __hip_bfloat16* o = (__hip_bfloat16*)out + (size_t)row * OUT_C;
            for (int c = lane; c < OUT_C; c += 64)
                o[c] = __float2bfloat16((c < F_TOT) ? fr[c] : funkey(gr[c - F_TOT]));
        }
    }
}

extern "C" void kernel_launch(void* const* d_in, const int* in_sizes, int n_in,
                              void* d_out, int out_size, void* d_ws, size_t ws_size,
                              hipStream_t stream) {
    const void* feat      = d_in[0];
    const void* att_rc    = d_in[1];
    const void* att_rp    = d_in[2];
    const void* etype_emb = d_in[3];
    const void* rid_emb   = d_in[4];
    const void* rc_W      = d_in[5];
    const void* rc_b      = d_in[6];
    const void* rp_W      = d_in[7];
    const void* rp_b      = d_in[8];
    const void* fe_W0     = d_in[9];
    const void* fe_b0     = d_in[10];
    const void* fe_W1     = d_in[11];
    const void* fe_b1     = d_in[12];
    const void* W_ni      = d_in[13];
    const void* W_nj      = d_in[14];
    const void* W_fij     = d_in[15];
    const void* W_node    = d_in[16];
    const void* attn      = d_in[17];
    const void* egat_bias = d_in[18];
    const void* Wm0       = d_in[19];
    const void* bm0       = d_in[20];
    const void* Wm1       = d_in[21];
    const void* bm1       = d_in[22];
    const int* src   = (const int*)d_in[23];
    const int* dst   = (const int*)d_in[24];
    const int* etype = (const int*)d_in[25];
    const int* rid   = (const int*)d_in[26];

    char* p = (char*)d_ws;
    auto alloc = [&](size_t bytes) {
        char* r = p;
        p += (bytes + 255) & ~(size_t)255;
        return r;
    };
    float*    feats  = (float*)alloc((size_t)N_NODES * F_TOT * 4);
    unsigned* gsrc   = (unsigned*)alloc((size_t)N_NODES * HO * 4);
    unsigned* gdst   = (unsigned*)alloc((size_t)N_NODES * 64 * 4);
    float*    h_att  = (float*)alloc((size_t)N_NODES * HO * 4);
    float*    T      = (float*)alloc((size_t)3 * NT_ROWS * HO * 4);
    unsigned* gmax   = (unsigned*)alloc((size_t)B_GRAPHS * F_TOT * 4);
    int*      flagp  = (int*)alloc(256);
    int*      rowptr = (int*)alloc((size_t)(N_NODES + 1) * 4);
    int*      cursor = (int*)alloc((size_t)N_NODES * 4);
    int*      cnt    = (int*)alloc((size_t)N_NODES * 4);
    uint4*    emeta  = (uint4*)alloc((size_t)N_EDGES * 16);

    k_detect<<<1, 256, 0, stream>>>(att_rc, flagp);
    hipMemsetAsync(cnt, 0, (size_t)N_NODES * 4, stream);
    hipMemsetAsync(gmax, 0, (size_t)B_GRAPHS * F_TOT * 4, stream);
    k_count<<<512, 256, 0, stream>>>(dst, cnt);
    k_scan<<<1, 1024, 0, stream>>>(cnt, rowptr, cursor);
    k_fill<<<1024, 256, 0, stream>>>(src, dst, etype, rid, att_rc, att_rp,
                                     cursor, emeta, flagp);
    k_init<<<(N_NODES + 63) / 64, 256, 0, stream>>>(feat, fe_W0, fe_b0, fe_W1, fe_b1,
                                                    feats, flagp);
    k_tables<<<3, 256, 0, stream>>>(etype_emb, rid_emb, rc_W, rc_b, rp_W, rp_b,
                                    W_fij, egat_bias, T, flagp);
    for (int l = 0; l < 3; l++) {
        int h_off = IN_DIM + l * HID;
        int out_off = IN_DIM + (l + 1) * HID;
        k_ngemm<<<(N_NODES + 63) / 64, 256, 0, stream>>>(feats, h_off, W_ni, W_nj, W_node, l,
                                                         gsrc, gdst, flagp);
        k_edge_fused<<<N_NODES / 4, 256, 0, stream>>>(T, attn, l, gsrc, gdst,
                                                      rowptr, emeta, h_att, flagp);
        k_mlp<<<(N_NODES + 63) / 64, 256, 0, stream>>>(h_att, Wm0, bm0, Wm1, bm1, l,
                                                       feats, h_off, out_off, flagp);
    }
    k_pool<<<dim3(B_GRAPHS, 128), 256, 0, stream>>>(feats, gmax);
    k_out<<<2048, 256, 0, stream>>>(feats, gmax, d_out, flagp);
}

// Round 7
// 1235.003 us; speedup vs baseline: 2.8935x; 1.0217x over previous
//
#include <hip/hip_runtime.h>
#include <hip/hip_bf16.h>
#include <math.h>

#define N_NODES 50000
#define N_EDGES 500000
#define B_GRAPHS 8
#define NPG 6250
#define HID 64
#define HO 128          // HEADS*HID
#define IN_DIM 10
#define F_TOT 266       // IN_DIM + 4*HID
#define OUT_C 532       // 2*F_TOT
#define NEG_SLOPE 0.2f
#define NT_ROWS 44      // 7 etype + 31 rid + 2 rc + 3 rp + 1 const
#define SCB 200         // scan blocks
#define SCH 250         // scan chunk (SCB*SCH == N_NODES)

typedef short bf16x8 __attribute__((ext_vector_type(8)));
typedef float f32x4 __attribute__((ext_vector_type(4)));

// dtype-agnostic float load: f32 flag chooses fp32 or bf16 interpretation
__device__ __forceinline__ float LD(const void* p, size_t i, int f32) {
    if (f32) return ((const float*)p)[i];
    unsigned u = ((const unsigned short*)p)[i];
    return __uint_as_float(u << 16);
}
__device__ __forceinline__ unsigned fkey(float f) {
    unsigned b = __float_as_uint(f);
    return (b & 0x80000000u) ? ~b : (b | 0x80000000u);
}
__device__ __forceinline__ float funkey(unsigned k) {
    unsigned b = (k & 0x80000000u) ? (k & 0x7fffffffu) : ~k;
    return __uint_as_float(b);
}
__device__ __forceinline__ unsigned short rnebf(float x) {
    unsigned u = __float_as_uint(x);
    return (unsigned short)((u + 0x7FFFu + ((u >> 16) & 1u)) >> 16);
}
__device__ __forceinline__ unsigned pk2(float lo, float hi) {
    return (unsigned)rnebf(lo) | ((unsigned)rnebf(hi) << 16);
}
__device__ __forceinline__ float plo(unsigned u) { return __uint_as_float(u << 16); }
__device__ __forceinline__ float phi(unsigned u) { return __uint_as_float(u & 0xFFFF0000u); }
// select bf16 half by shift s (16 = lo half, 0 = hi half)
__device__ __forceinline__ float sel16(unsigned w, int s) {
    return __uint_as_float((w << s) & 0xFFFF0000u);
}
// 32-lane half-wave sum: both halves reduced independently (4 DPP + 1 shfl)
__device__ __forceinline__ float halfsum(float x) {
    x += __int_as_float(__builtin_amdgcn_update_dpp(0, __float_as_int(x), 0xB1, 0xF, 0xF, true));
    x += __int_as_float(__builtin_amdgcn_update_dpp(0, __float_as_int(x), 0x4E, 0xF, 0xF, true));
    x += __int_as_float(__builtin_amdgcn_update_dpp(0, __float_as_int(x), 0x141, 0xF, 0xF, true));
    x += __int_as_float(__builtin_amdgcn_update_dpp(0, __float_as_int(x), 0x140, 0xF, 0xF, true));
    x += __shfl_xor(x, 16, 64);
    return x;
}

// ---------------- dtype detection ------------------------------------------
__global__ void k_detect(const void* __restrict__ att_rc, int* __restrict__ flagp) {
    __shared__ int cnt;
    if (threadIdx.x == 0) cnt = 0;
    __syncthreads();
    const unsigned short* w = (const unsigned short*)att_rc;
    int c = 0;
    for (int i = threadIdx.x; i < 8192; i += 256) {
        unsigned e = (w[i] >> 7) & 0xFF;
        if (e >= 0xC0) c++;
    }
    atomicAdd(&cnt, c);
    __syncthreads();
    if (threadIdx.x == 0) *flagp = (cnt > 8) ? 1 : 0;
}

// ---------------- CSR build ------------------------------------------------
__global__ void k_count(const int* __restrict__ dst, int* __restrict__ cnt) {
    int i = blockIdx.x * blockDim.x + threadIdx.x;
    int stride = gridDim.x * blockDim.x;
    for (int e = i; e < N_EDGES; e += stride) atomicAdd(&cnt[dst[e]], 1);
}

// parallel scan, stage 1: per-chunk sums
__global__ void k_scan1(const int* __restrict__ cnt, int* __restrict__ bsum) {
    __shared__ int red[256];
    int b = blockIdx.x, t = threadIdx.x;
    red[t] = (t < SCH) ? cnt[b * SCH + t] : 0;
    __syncthreads();
    for (int off = 128; off; off >>= 1) {
        if (t < off) red[t] += red[t + off];
        __syncthreads();
    }
    if (t == 0) bsum[b] = red[0];
}
// stage 2: exclusive scan of the 200 chunk sums (one tiny block)
__global__ void k_scan2(const int* __restrict__ bsum, int* __restrict__ boff) {
    __shared__ int ts[256];
    int t = threadIdx.x;
    int v = (t < SCB) ? bsum[t] : 0;
    ts[t] = v;
    __syncthreads();
    for (int off = 1; off < 256; off <<= 1) {
        int u = (t >= off) ? ts[t - off] : 0;
        __syncthreads();
        ts[t] += u;
        __syncthreads();
    }
    if (t < SCB) boff[t] = ts[t] - v;
}
// stage 3: per-chunk scan + write rowptr/cursor
__global__ void k_scan3(const int* __restrict__ cnt, const int* __restrict__ boff,
                        int* __restrict__ rowptr, int* __restrict__ cursor) {
    __shared__ int ts[256];
    int b = blockIdx.x, t = threadIdx.x;
    int base = b * SCH;
    int v = (t < SCH) ? cnt[base + t] : 0;
    ts[t] = v;
    __syncthreads();
    for (int off = 1; off < 256; off <<= 1) {
        int u = (t >= off) ? ts[t - off] : 0;
        __syncthreads();
        ts[t] += u;
        __syncthreads();
    }
    if (t < SCH) {
        int r = boff[b] + ts[t] - v;
        rowptr[base + t] = r;
        cursor[base + t] = r;
    }
    if (b == SCB - 1 && t == SCH - 1) rowptr[N_NODES] = boff[b] + ts[t];
}

// emeta.w = etype | rid<<3 | src<<8   (src < 65536)
__global__ void k_fill(const int* __restrict__ src, const int* __restrict__ dst,
                       const int* __restrict__ etype, const int* __restrict__ rid,
                       const void* __restrict__ att_rc, const void* __restrict__ att_rp,
                       int* __restrict__ cursor, uint4* __restrict__ emeta,
                       const int* __restrict__ flagp) {
    const int f32 = *flagp;
    int i = blockIdx.x * blockDim.x + threadIdx.x;
    int stride = gridDim.x * blockDim.x;
    for (int e = i; e < N_EDGES; e += stride) {
        int d = dst[e];
        int j = atomicAdd(&cursor[d], 1);
        float rc0 = LD(att_rc, 2 * (size_t)e, f32), rc1 = LD(att_rc, 2 * (size_t)e + 1, f32);
        float rp0 = LD(att_rp, 3 * (size_t)e, f32), rp1 = LD(att_rp, 3 * (size_t)e + 1, f32),
              rp2 = LD(att_rp, 3 * (size_t)e + 2, f32);
        uint4 m;
        m.x = pk2(rc0, rc1);
        m.y = pk2(rp0, rp1);
        m.z = pk2(rp2, 0.f);
        m.w = (unsigned)(etype[e] | (rid[e] << 3) | ((unsigned)src[e] << 8));
        emeta[j] = m;
    }
}

// ---------------- initial feature MLP --------------------------------------
__global__ void k_init(const void* __restrict__ feat,
                       const void* __restrict__ W0, const void* __restrict__ b0,
                       const void* __restrict__ W1, const void* __restrict__ b1,
                       float* __restrict__ feats, const int* __restrict__ flagp) {
    const int f32 = *flagp;
    __shared__ float sf[64 * 12];
    __shared__ float sW0[IN_DIM * 64];
    __shared__ float sb0[64], sb1[64];
    __shared__ float sh[64 * 64];
    __shared__ float sW1[64 * 64];
    int tid = threadIdx.x, n0 = blockIdx.x * 64;
    for (int i = tid; i < IN_DIM * 64; i += 256) sW0[i] = LD(W0, i, f32);
    for (int i = tid; i < 64; i += 256) { sb0[i] = LD(b0, i, f32); sb1[i] = LD(b1, i, f32); }
    for (int i = tid; i < 64 * 64; i += 256) sW1[i] = LD(W1, i, f32);
    for (int i = tid; i < 64 * IN_DIM; i += 256) {
        int n = n0 + i / IN_DIM, c = i % IN_DIM;
        sf[(i / IN_DIM) * 12 + c] = (n < N_NODES) ? LD(feat, (size_t)n * IN_DIM + c, f32) : 0.f;
    }
    __syncthreads();
    int ng = tid / 16, cg = tid % 16;
    float acc[4][4];
    #pragma unroll
    for (int i = 0; i < 4; i++)
        #pragma unroll
        for (int j = 0; j < 4; j++) acc[i][j] = sb0[cg * 4 + j];
    #pragma unroll
    for (int k = 0; k < IN_DIM; k++)
        #pragma unroll
        for (int i = 0; i < 4; i++) {
            float a = sf[(ng * 4 + i) * 12 + k];
            #pragma unroll
            for (int j = 0; j < 4; j++) acc[i][j] += a * sW0[k * 64 + cg * 4 + j];
        }
    #pragma unroll
    for (int i = 0; i < 4; i++)
        #pragma unroll
        for (int j = 0; j < 4; j++) sh[(ng * 4 + i) * 64 + cg * 4 + j] = fmaxf(acc[i][j], 0.f);
    __syncthreads();
    float o[4][4];
    #pragma unroll
    for (int i = 0; i < 4; i++)
        #pragma unroll
        for (int j = 0; j < 4; j++) o[i][j] = sb1[cg * 4 + j];
    for (int k = 0; k < 64; k++) {
        float4 bv = *(const float4*)&sW1[k * 64 + cg * 4];
        #pragma unroll
        for (int i = 0; i < 4; i++) {
            float a = sh[(ng * 4 + i) * 64 + k];
            o[i][0] += a * bv.x; o[i][1] += a * bv.y;
            o[i][2] += a * bv.z; o[i][3] += a * bv.w;
        }
    }
    #pragma unroll
    for (int i = 0; i < 4; i++) {
        int n = n0 + ng * 4 + i;
        if (n < N_NODES) {
            float* r = feats + (size_t)n * F_TOT;
            #pragma unroll
            for (int j = 0; j < 4; j++) r[IN_DIM + cg * 4 + j] = o[i][j];
        }
    }
    for (int i = tid; i < 64 * IN_DIM; i += 256) {
        int n = n0 + i / IN_DIM, c = i % IN_DIM;
        if (n < N_NODES) feats[(size_t)n * F_TOT + c] = sf[(i / IN_DIM) * 12 + c];
    }
}

// ---------------- fused edge tables ----------------------------------------
__global__ void k_tables(const void* __restrict__ etype_emb, const void* __restrict__ rid_emb,
                         const void* __restrict__ rc_W, const void* __restrict__ rc_b,
                         const void* __restrict__ rp_W, const void* __restrict__ rp_b,
                         const void* __restrict__ W_fij, const void* __restrict__ egat_bias,
                         float* __restrict__ T, const int* __restrict__ flagp) {
    const int f32 = *flagp;
    int l = blockIdx.x;
    __shared__ float S[NT_ROWS * HID];
    __shared__ float W[HID * HO];
    for (int i = threadIdx.x; i < 7 * HID; i += 256) S[i] = LD(etype_emb, i, f32);
    for (int i = threadIdx.x; i < 31 * HID; i += 256) S[7 * HID + i] = LD(rid_emb, i, f32);
    for (int i = threadIdx.x; i < 2 * HID; i += 256) S[38 * HID + i] = LD(rc_W, i, f32);
    for (int i = threadIdx.x; i < 3 * HID; i += 256) S[40 * HID + i] = LD(rp_W, i, f32);
    for (int i = threadIdx.x; i < HID; i += 256)
        S[43 * HID + i] = LD(rc_b, i, f32) + LD(rp_b, i, f32);
    for (int i = threadIdx.x; i < HID * HO; i += 256)
        W[i] = LD(W_fij, (size_t)l * HID * HO + i, f32);
    __syncthreads();
    for (int idx = threadIdx.x; idx < NT_ROWS * HO; idx += 256) {
        int r = idx / HO, c = idx % HO;
        float acc = (r == 43) ? LD(egat_bias, l * HO + c, f32) : 0.f;
        for (int k = 0; k < HID; k++) acc += S[r * HID + k] * W[k * HO + c];
        T[(size_t)l * NT_ROWS * HO + idx] = acc;
    }
}

// ---------------- node GEMMs via MFMA -> packed bf16 gather buffers --------
__global__ void __launch_bounds__(256) k_ngemm(
        const float* __restrict__ feats, int h_off,
        const void* __restrict__ W_ni, const void* __restrict__ W_nj,
        const void* __restrict__ W_node, int l,
        unsigned* __restrict__ gsrc, unsigned* __restrict__ gdst,
        const int* __restrict__ flagp) {
    const int f32 = *flagp;
    __shared__ unsigned short Xs[64 * 72];
    __shared__ unsigned short Ws[384 * 72];
    int tid = threadIdx.x, n0 = blockIdx.x * 64;
    for (int i = tid; i < 64 * 64; i += 256) {
        int n = i >> 6, c = i & 63, gn = n0 + n;
        Xs[n * 72 + c] = rnebf((gn < N_NODES) ? feats[(size_t)gn * F_TOT + h_off + c] : 0.f);
    }
    for (int i = tid; i < 3 * 64 * 128; i += 256) {
        int m = i >> 13, r = i & 8191, k = r >> 7, c = r & 127;
        const void* W = (m == 0) ? W_ni : (m == 1) ? W_nj : W_node;
        Ws[(m * 128 + c) * 72 + k] = rnebf(LD(W, (size_t)l * 8192 + k * 128 + c, f32));
    }
    __syncthreads();
    int wid = tid >> 6, lane = tid & 63;
    int row0 = wid * 16, mrow = lane & 15, quad = lane >> 4;
    bf16x8 a0 = *(const bf16x8*)&Xs[(row0 + mrow) * 72 + quad * 8];
    bf16x8 a1 = *(const bf16x8*)&Xs[(row0 + mrow) * 72 + 32 + quad * 8];
    f32x4 accA[8], accB[8];
    #pragma unroll
    for (int j = 0; j < 8; j++) { accA[j] = (f32x4){0,0,0,0}; accB[j] = (f32x4){0,0,0,0}; }
    #pragma unroll
    for (int j = 0; j < 8; j++) {
        bf16x8 b0 = *(const bf16x8*)&Ws[(0 * 128 + j * 16 + mrow) * 72 + quad * 8];
        bf16x8 b1 = *(const bf16x8*)&Ws[(0 * 128 + j * 16 + mrow) * 72 + 32 + quad * 8];
        accA[j] = __builtin_amdgcn_mfma_f32_16x16x32_bf16(a0, b0, accA[j], 0, 0, 0);
        accA[j] = __builtin_amdgcn_mfma_f32_16x16x32_bf16(a1, b1, accA[j], 0, 0, 0);
        bf16x8 c0 = *(const bf16x8*)&Ws[(2 * 128 + j * 16 + mrow) * 72 + quad * 8];
        bf16x8 c1 = *(const bf16x8*)&Ws[(2 * 128 + j * 16 + mrow) * 72 + 32 + quad * 8];
        accB[j] = __builtin_amdgcn_mfma_f32_16x16x32_bf16(a0, c0, accB[j], 0, 0, 0);
        accB[j] = __builtin_amdgcn_mfma_f32_16x16x32_bf16(a1, c1, accB[j], 0, 0, 0);
    }
    #pragma unroll
    for (int j = 0; j < 4; j++) {
        int c = j * 16 + mrow;
        #pragma unroll
        for (int r = 0; r < 4; r++) {
            int gn = n0 + row0 + quad * 4 + r;
            if (gn < N_NODES) {
                uint2 v;
                v.x = pk2(accA[j][r], accA[j + 4][r]);
                v.y = pk2(accB[j][r], accB[j + 4][r]);
                *(uint2*)&gsrc[(size_t)gn * 128 + c * 2] = v;
            }
        }
    }
    f32x4 accC[8];
    #pragma unroll
    for (int j = 0; j < 8; j++) accC[j] = (f32x4){0,0,0,0};
    #pragma unroll
    for (int j = 0; j < 8; j++) {
        bf16x8 b0 = *(const bf16x8*)&Ws[(1 * 128 + j * 16 + mrow) * 72 + quad * 8];
        bf16x8 b1 = *(const bf16x8*)&Ws[(1 * 128 + j * 16 + mrow) * 72 + 32 + quad * 8];
        accC[j] = __builtin_amdgcn_mfma_f32_16x16x32_bf16(a0, b0, accC[j], 0, 0, 0);
        accC[j] = __builtin_amdgcn_mfma_f32_16x16x32_bf16(a1, b1, accC[j], 0, 0, 0);
    }
    #pragma unroll
    for (int j = 0; j < 4; j++) {
        int c = j * 16 + mrow;
        #pragma unroll
        for (int r = 0; r < 4; r++) {
            int gn = n0 + row0 + quad * 4 + r;
            if (gn < N_NODES)
                gdst[(size_t)gn * 64 + c] = pk2(accC[j][r], accC[j + 4][r]);
        }
    }
}

// ---------------- fused edge phase: head-split lanes ------------------------
// lane L: head h = L>>5, t = L&31, cols {h*64+2t, h*64+2t+1}
__global__ void __launch_bounds__(256) k_edge_fused(
        const float* __restrict__ T, const void* __restrict__ attn, int l,
        const unsigned* __restrict__ gsrc, const unsigned* __restrict__ gdst,
        const int* __restrict__ rowptr, const uint4* __restrict__ emeta,
        float* __restrict__ h_att, const int* __restrict__ flagp) {
    const int f32 = *flagp;
    __shared__ float Ts[38 * HO];
    const float* Tl = T + (size_t)l * NT_ROWS * HO;
    for (int i4 = threadIdx.x; i4 < 38 * HO / 4; i4 += 256)
        ((float4*)Ts)[i4] = ((const float4*)Tl)[i4];
    int lane = threadIdx.x & 63;
    int hh = lane >> 5, t = lane & 31;
    int col0 = hh * 64 + 2 * t;
    int s = hh ? 0 : 16;   // bf16 half-select shift
    float Cp0[6], Cp1[6];
    #pragma unroll
    for (int r = 0; r < 6; r++) {
        Cp0[r] = Tl[(38 + r) * HO + col0];
        Cp1[r] = Tl[(38 + r) * HO + col0 + 1];
    }
    float at0 = LD(attn, l * HO + col0, f32), at1 = LD(attn, l * HO + col0 + 1, f32);
    __syncthreads();
    int d = blockIdx.x * 4 + (threadIdx.x >> 6);
    int jb = rowptr[d], je = rowptr[d + 1];
    uint2 gd = *(const uint2*)&gdst[(size_t)d * 64 + 2 * t];
    float nj0 = sel16(gd.x, s) + Cp0[5];   // fold const row into nj
    float nj1 = sel16(gd.y, s) + Cp1[5];
    float m = -INFINITY, lsum = 0.f, acc0 = 0.f, acc1 = 0.f;

    auto logits = [&](const uint4& em, const uint4& g,
                      float& e, float& h0, float& h1) {
        unsigned wm = em.w;
        int et = (int)(wm & 7u), ri = (int)((wm >> 3) & 31u);
        float rc0 = plo(em.x), rc1 = phi(em.x);
        float rp0 = plo(em.y), rp1 = phi(em.y), rp2 = plo(em.z);
        float2 tE = *(const float2*)&Ts[et * HO + col0];
        float2 tR = *(const float2*)&Ts[(7 + ri) * HO + col0];
        float ni0 = sel16(g.x, s), ni1 = sel16(g.z, s);
        h0 = sel16(g.y, s); h1 = sel16(g.w, s);
        float x0 = ni0 + nj0 + tE.x + tR.x
                 + rc0 * Cp0[0] + rc1 * Cp0[1] + rp0 * Cp0[2] + rp1 * Cp0[3] + rp2 * Cp0[4];
        float x1 = ni1 + nj1 + tE.y + tR.y
                 + rc0 * Cp1[0] + rc1 * Cp1[1] + rp0 * Cp1[2] + rp1 * Cp1[3] + rp2 * Cp1[4];
        x0 = (x0 > 0.f) ? x0 : NEG_SLOPE * x0;
        x1 = (x1 > 0.f) ? x1 : NEG_SLOPE * x1;
        e = halfsum(x0 * at0 + x1 * at1);
    };
    auto update = [&](float e, float h0, float h1) {
        float nm = fmaxf(m, e);
        float sc = __expf(m - nm), w = __expf(e - nm);
        lsum = lsum * sc + w;
        acc0 = acc0 * sc + w * h0;
        acc1 = acc1 * sc + w * h1;
        m = nm;
    };
    auto fetch = [&](int j, uint4& em, uint4& g) {
        em = emeta[j];
        g = *(const uint4*)&gsrc[(size_t)(em.w >> 8) * 128 + 4 * t];
    };

    uint4 emA = make_uint4(0,0,0,0), emB = make_uint4(0,0,0,0);
    uint4 gA = make_uint4(0,0,0,0), gB = make_uint4(0,0,0,0);
    int j = jb;
    if (j < je)     fetch(j, emA, gA);
    if (j + 1 < je) fetch(j + 1, emB, gB);
    while (j + 2 <= je) {
        float eA, h0A, h1A, eB, h0B, h1B;
        logits(emA, gA, eA, h0A, h1A);   // independent halfsum chains
        logits(emB, gB, eB, h0B, h1B);
        if (j + 2 < je) fetch(j + 2, emA, gA);
        if (j + 3 < je) fetch(j + 3, emB, gB);
        update(eA, h0A, h1A);
        update(eB, h0B, h1B);
        j += 2;
    }
    if (j < je) {
        float e, h0, h1;
        logits(emA, gA, e, h0, h1);
        update(e, h0, h1);
    }
    float inv = 1.f / (lsum + 1e-9f);
    float2 o;
    o.x = acc0 * inv;
    o.y = acc1 * inv;
    *(float2*)&h_att[(size_t)d * HO + col0] = o;
}

// ---------------- node MLP + residual via MFMA ------------------------------
__global__ void __launch_bounds__(256) k_mlp(
        const float* __restrict__ h_att,
        const void* __restrict__ Wm0, const void* __restrict__ bm0,
        const void* __restrict__ Wm1, const void* __restrict__ bm1, int l,
        float* __restrict__ feats, int prev_off, int out_off,
        const int* __restrict__ flagp) {
    const int f32 = *flagp;
    __shared__ unsigned short Xs[64 * 136];
    __shared__ unsigned short W0T[128 * 136];
    __shared__ unsigned short W1T[64 * 136];
    __shared__ float sb0[HO], sb1[64];
    int tid = threadIdx.x, n0 = blockIdx.x * 64;
    for (int i = tid; i < 64 * 128; i += 256) {
        int n = i >> 7, c = i & 127, gn = n0 + n;
        Xs[n * 136 + c] = rnebf((gn < N_NODES) ? h_att[(size_t)gn * HO + c] : 0.f);
    }
    for (int i = tid; i < 128 * 128; i += 256) {
        int k = i >> 7, c = i & 127;
        W0T[c * 136 + k] = rnebf(LD(Wm0, (size_t)l * 16384 + k * 128 + c, f32));
    }
    for (int i = tid; i < 128 * 64; i += 256) {
        int k = i >> 6, c = i & 63;
        W1T[c * 136 + k] = rnebf(LD(Wm1, (size_t)l * 8192 + k * 64 + c, f32));
    }
    for (int i = tid; i < HO; i += 256) sb0[i] = LD(bm0, l * HO + i, f32);
    for (int i = tid; i < 64; i += 256) sb1[i] = LD(bm1, l * 64 + i, f32);
    __syncthreads();
    int wid = tid >> 6, lane = tid & 63;
    int row0 = wid * 16, mrow = lane & 15, quad = lane >> 4;
    f32x4 acc[8];
    #pragma unroll
    for (int j = 0; j < 8; j++) {
        float b = sb0[j * 16 + mrow];
        acc[j] = (f32x4){b, b, b, b};
    }
    #pragma unroll
    for (int ks = 0; ks < 4; ks++) {
        bf16x8 a = *(const bf16x8*)&Xs[(row0 + mrow) * 136 + ks * 32 + quad * 8];
        #pragma unroll
        for (int j = 0; j < 8; j++) {
            bf16x8 b = *(const bf16x8*)&W0T[(j * 16 + mrow) * 136 + ks * 32 + quad * 8];
            acc[j] = __builtin_amdgcn_mfma_f32_16x16x32_bf16(a, b, acc[j], 0, 0, 0);
        }
    }
    #pragma unroll
    for (int j = 0; j < 8; j++)
        #pragma unroll
        for (int r = 0; r < 4; r++)
            Xs[(row0 + quad * 4 + r) * 136 + j * 16 + mrow] = rnebf(fmaxf(acc[j][r], 0.f));
    f32x4 o[4];
    #pragma unroll
    for (int j = 0; j < 4; j++) {
        float b = sb1[j * 16 + mrow];
        o[j] = (f32x4){b, b, b, b};
    }
    #pragma unroll
    for (int ks = 0; ks < 4; ks++) {
        bf16x8 a = *(const bf16x8*)&Xs[(row0 + mrow) * 136 + ks * 32 + quad * 8];
        #pragma unroll
        for (int j = 0; j < 4; j++) {
            bf16x8 b = *(const bf16x8*)&W1T[(j * 16 + mrow) * 136 + ks * 32 + quad * 8];
            o[j] = __builtin_amdgcn_mfma_f32_16x16x32_bf16(a, b, o[j], 0, 0, 0);
        }
    }
    #pragma unroll
    for (int j = 0; j < 4; j++) {
        int c = j * 16 + mrow;
        #pragma unroll
        for (int r = 0; r < 4; r++) {
            int gn = n0 + row0 + quad * 4 + r;
            if (gn < N_NODES) {
                float* rw = feats + (size_t)gn * F_TOT;
                rw[out_off + c] = o[j][r] + rw[prev_off + c];
            }
        }
    }
}

// ---------------- graph max pool -------------------------------------------
__global__ void k_pool(const float* __restrict__ feats, unsigned* __restrict__ gmax) {
    int g = blockIdx.x;
    int chunk = blockIdx.y;
    int t = threadIdx.x;
    const int CS = 49;
    int nb = chunk * CS;
    int ne = (nb + CS < NPG) ? nb + CS : NPG;
    float m0 = -INFINITY, m1 = -INFINITY;
    for (int n = nb; n < ne; n++) {
        const float* row = feats + (size_t)(g * NPG + n) * F_TOT;
        m0 = fmaxf(m0, row[t]);
        if (t + 256 < F_TOT) m1 = fmaxf(m1, row[t + 256]);
    }
    atomicMax(&gmax[g * F_TOT + t], fkey(m0));
    if (t + 256 < F_TOT) atomicMax(&gmax[g * F_TOT + t + 256], fkey(m1));
}

// ---------------- output write: wave per row --------------------------------
__global__ void k_out(const float* __restrict__ feats, const unsigned* __restrict__ gmax,
                      void* __restrict__ out, const int* __restrict__ flagp) {
    const int f32 = *flagp;
    int lane = threadIdx.x & 63;
    int wave = (blockIdx.x * blockDim.x + threadIdx.x) >> 6;
    int nw = (gridDim.x * blockDim.x) >> 6;
    for (int row = wave; row < B_GRAPHS * NPG; row += nw) {
        int g = row / NPG;
        const float* fr = feats + (size_t)row * F_TOT;
        const unsigned* gr = gmax + g * F_TOT;
        if (f32) {
            float* o = (float*)out + (size_t)row * OUT_C;
            for (int c = lane; c < OUT_C; c += 64)
                o[c] = (c < F_TOT) ? fr[c] : funkey(gr[c - F_TOT]);
        } else {
            __hip_bfloat16* o = (__hip_bfloat16*)out + (size_t)row * OUT_C;
            for (int c = lane; c < OUT_C; c += 64)
                o[c] = __float2bfloat16((c < F_TOT) ? fr[c] : funkey(gr[c - F_TOT]));
        }
    }
}

extern "C" void kernel_launch(void* const* d_in, const int* in_sizes, int n_in,
                              void* d_out, int out_size, void* d_ws, size_t ws_size,
                              hipStream_t stream) {
    const void* feat      = d_in[0];
    const void* att_rc    = d_in[1];
    const void* att_rp    = d_in[2];
    const void* etype_emb = d_in[3];
    const void* rid_emb   = d_in[4];
    const void* rc_W      = d_in[5];
    const void* rc_b      = d_in[6];
    const void* rp_W      = d_in[7];
    const void* rp_b      = d_in[8];
    const void* fe_W0     = d_in[9];
    const void* fe_b0     = d_in[10];
    const void* fe_W1     = d_in[11];
    const void* fe_b1     = d_in[12];
    const void* W_ni      = d_in[13];
    const void* W_nj      = d_in[14];
    const void* W_fij     = d_in[15];
    const void* W_node    = d_in[16];
    const void* attn      = d_in[17];
    const void* egat_bias = d_in[18];
    const void* Wm0       = d_in[19];
    const void* bm0       = d_in[20];
    const void* Wm1       = d_in[21];
    const void* bm1       = d_in[22];
    const int* src   = (const int*)d_in[23];
    const int* dst   = (const int*)d_in[24];
    const int* etype = (const int*)d_in[25];
    const int* rid   = (const int*)d_in[26];

    char* p = (char*)d_ws;
    auto alloc = [&](size_t bytes) {
        char* r = p;
        p += (bytes + 255) & ~(size_t)255;
        return r;
    };
    float*    feats  = (float*)alloc((size_t)N_NODES * F_TOT * 4);
    unsigned* gsrc   = (unsigned*)alloc((size_t)N_NODES * HO * 4);
    unsigned* gdst   = (unsigned*)alloc((size_t)N_NODES * 64 * 4);
    float*    h_att  = (float*)alloc((size_t)N_NODES * HO * 4);
    float*    T      = (float*)alloc((size_t)3 * NT_ROWS * HO * 4);
    unsigned* gmax   = (unsigned*)alloc((size_t)B_GRAPHS * F_TOT * 4);
    int*      flagp  = (int*)alloc(256);
    int*      rowptr = (int*)alloc((size_t)(N_NODES + 1) * 4);
    int*      cursor = (int*)alloc((size_t)N_NODES * 4);
    int*      cnt    = (int*)alloc((size_t)N_NODES * 4);
    int*      bsum   = (int*)alloc((size_t)SCB * 4);
    int*      boff   = (int*)alloc((size_t)SCB * 4);
    uint4*    emeta  = (uint4*)alloc((size_t)N_EDGES * 16);

    k_detect<<<1, 256, 0, stream>>>(att_rc, flagp);
    hipMemsetAsync(cnt, 0, (size_t)N_NODES * 4, stream);
    hipMemsetAsync(gmax, 0, (size_t)B_GRAPHS * F_TOT * 4, stream);
    k_count<<<512, 256, 0, stream>>>(dst, cnt);
    k_scan1<<<SCB, 256, 0, stream>>>(cnt, bsum);
    k_scan2<<<1, 256, 0, stream>>>(bsum, boff);
    k_scan3<<<SCB, 256, 0, stream>>>(cnt, boff, rowptr, cursor);
    k_fill<<<1024, 256, 0, stream>>>(src, dst, etype, rid, att_rc, att_rp,
                                     cursor, emeta, flagp);
    k_init<<<(N_NODES + 63) / 64, 256, 0, stream>>>(feat, fe_W0, fe_b0, fe_W1, fe_b1,
                                                    feats, flagp);
    k_tables<<<3, 256, 0, stream>>>(etype_emb, rid_emb, rc_W, rc_b, rp_W, rp_b,
                                    W_fij, egat_bias, T, flagp);
    for (int l = 0; l < 3; l++) {
        int h_off = IN_DIM + l * HID;
        int out_off = IN_DIM + (l + 1) * HID;
        k_ngemm<<<(N_NODES + 63) / 64, 256, 0, stream>>>(feats, h_off, W_ni, W_nj, W_node, l,
                                                         gsrc, gdst, flagp);
        k_edge_fused<<<N_NODES / 4, 256, 0, stream>>>(T, attn, l, gsrc, gdst,
                                                      rowptr, emeta, h_att, flagp);
        k_mlp<<<(N_NODES + 63) / 64, 256, 0, stream>>>(h_att, Wm0, bm0, Wm1, bm1, l,
                                                       feats, h_off, out_off, flagp);
    }
    k_pool<<<dim3(B_GRAPHS, 128), 256, 0, stream>>>(feats, gmax);
    k_out<<<2048, 256, 0, stream>>>(feats, gmax, d_out, flagp);
}

// Round 8
// 815.413 us; speedup vs baseline: 4.3824x; 1.5146x over previous
//
#include <hip/hip_runtime.h>
#include <hip/hip_bf16.h>
#include <math.h>

#define N_NODES 50000
#define N_EDGES 500000
#define B_GRAPHS 8
#define NPG 6250
#define HID 64
#define HO 128          // HEADS*HID
#define IN_DIM 10
#define F_TOT 266       // IN_DIM + 4*HID
#define OUT_C 532       // 2*F_TOT
#define NEG_SLOPE 0.2f
#define NT_ROWS 44      // 7 etype + 31 rid + 2 rc + 3 rp + 1 const
#define SCB 200         // scan blocks
#define SCH 250         // scan chunk (SCB*SCH == N_NODES)

typedef short bf16x8 __attribute__((ext_vector_type(8)));
typedef float f32x4 __attribute__((ext_vector_type(4)));

// dtype-agnostic float load: f32 flag chooses fp32 or bf16 interpretation
__device__ __forceinline__ float LD(const void* p, size_t i, int f32) {
    if (f32) return ((const float*)p)[i];
    unsigned u = ((const unsigned short*)p)[i];
    return __uint_as_float(u << 16);
}
__device__ __forceinline__ unsigned fkey(float f) {
    unsigned b = __float_as_uint(f);
    return (b & 0x80000000u) ? ~b : (b | 0x80000000u);
}
__device__ __forceinline__ float funkey(unsigned k) {
    unsigned b = (k & 0x80000000u) ? (k & 0x7fffffffu) : ~k;
    return __uint_as_float(b);
}
__device__ __forceinline__ unsigned short rnebf(float x) {
    unsigned u = __float_as_uint(x);
    return (unsigned short)((u + 0x7FFFu + ((u >> 16) & 1u)) >> 16);
}
__device__ __forceinline__ unsigned pk2(float lo, float hi) {
    return (unsigned)rnebf(lo) | ((unsigned)rnebf(hi) << 16);
}
__device__ __forceinline__ float plo(unsigned u) { return __uint_as_float(u << 16); }
__device__ __forceinline__ float phi(unsigned u) { return __uint_as_float(u & 0xFFFF0000u); }
// wave64 sum: 4 DPP steps (VALU pipe), then 2 shfl across rows
__device__ __forceinline__ float wsum(float x) {
    x += __int_as_float(__builtin_amdgcn_update_dpp(0, __float_as_int(x), 0xB1, 0xF, 0xF, true));
    x += __int_as_float(__builtin_amdgcn_update_dpp(0, __float_as_int(x), 0x4E, 0xF, 0xF, true));
    x += __int_as_float(__builtin_amdgcn_update_dpp(0, __float_as_int(x), 0x141, 0xF, 0xF, true));
    x += __int_as_float(__builtin_amdgcn_update_dpp(0, __float_as_int(x), 0x140, 0xF, 0xF, true));
    x += __shfl_xor(x, 16, 64);
    x += __shfl_xor(x, 32, 64);
    return x;
}

// ---------------- dtype detection ------------------------------------------
__global__ void k_detect(const void* __restrict__ att_rc, int* __restrict__ flagp) {
    __shared__ int cnt;
    if (threadIdx.x == 0) cnt = 0;
    __syncthreads();
    const unsigned short* w = (const unsigned short*)att_rc;
    int c = 0;
    for (int i = threadIdx.x; i < 8192; i += 256) {
        unsigned e = (w[i] >> 7) & 0xFF;
        if (e >= 0xC0) c++;
    }
    atomicAdd(&cnt, c);
    __syncthreads();
    if (threadIdx.x == 0) *flagp = (cnt > 8) ? 1 : 0;
}

// ---------------- weight pre-pack to bf16 (transposed LDS layouts) ----------
// pw_n[((l*3+m)*128+c)*64+k], pw_m0[(l*128+c)*128+k], pw_m1[(l*64+c)*128+k]
__global__ void k_wprep(const void* __restrict__ W_ni, const void* __restrict__ W_nj,
                        const void* __restrict__ W_node, const void* __restrict__ Wm0,
                        const void* __restrict__ Wm1,
                        unsigned short* __restrict__ pw_n,
                        unsigned short* __restrict__ pw_m0,
                        unsigned short* __restrict__ pw_m1,
                        const int* __restrict__ flagp) {
    const int f32 = *flagp;
    int i = blockIdx.x * 256 + threadIdx.x;
    if (i < 73728) {                      // 3l x 3m x 128c x 64k
        int k = i & 63, c = (i >> 6) & 127, lm = i >> 13;
        int m = lm % 3, l = lm / 3;
        const void* W = (m == 0) ? W_ni : (m == 1) ? W_nj : W_node;
        pw_n[i] = rnebf(LD(W, (size_t)l * 8192 + k * 128 + c, f32));
    } else if (i < 73728 + 49152) {       // 3l x 128c x 128k
        int j = i - 73728;
        int k = j & 127, c = (j >> 7) & 127, l = j >> 14;
        pw_m0[j] = rnebf(LD(Wm0, (size_t)l * 16384 + k * 128 + c, f32));
    } else if (i < 147456) {              // 3l x 64c x 128k
        int j = i - 122880;
        int k = j & 127, c = (j >> 7) & 63, l = j >> 13;
        pw_m1[j] = rnebf(LD(Wm1, (size_t)l * 8192 + k * 64 + c, f32));
    }
}

// ---------------- CSR build ------------------------------------------------
__global__ void k_count(const int* __restrict__ dst, int* __restrict__ cnt) {
    int i = blockIdx.x * blockDim.x + threadIdx.x;
    int stride = gridDim.x * blockDim.x;
    for (int e = i; e < N_EDGES; e += stride) atomicAdd(&cnt[dst[e]], 1);
}

__global__ void k_scan1(const int* __restrict__ cnt, int* __restrict__ bsum) {
    __shared__ int red[256];
    int b = blockIdx.x, t = threadIdx.x;
    red[t] = (t < SCH) ? cnt[b * SCH + t] : 0;
    __syncthreads();
    for (int off = 128; off; off >>= 1) {
        if (t < off) red[t] += red[t + off];
        __syncthreads();
    }
    if (t == 0) bsum[b] = red[0];
}
__global__ void k_scan2(const int* __restrict__ bsum, int* __restrict__ boff) {
    __shared__ int ts[256];
    int t = threadIdx.x;
    int v = (t < SCB) ? bsum[t] : 0;
    ts[t] = v;
    __syncthreads();
    for (int off = 1; off < 256; off <<= 1) {
        int u = (t >= off) ? ts[t - off] : 0;
        __syncthreads();
        ts[t] += u;
        __syncthreads();
    }
    if (t < SCB) boff[t] = ts[t] - v;
}
__global__ void k_scan3(const int* __restrict__ cnt, const int* __restrict__ boff,
                        int* __restrict__ rowptr, int* __restrict__ cursor) {
    __shared__ int ts[256];
    int b = blockIdx.x, t = threadIdx.x;
    int base = b * SCH;
    int v = (t < SCH) ? cnt[base + t] : 0;
    ts[t] = v;
    __syncthreads();
    for (int off = 1; off < 256; off <<= 1) {
        int u = (t >= off) ? ts[t - off] : 0;
        __syncthreads();
        ts[t] += u;
        __syncthreads();
    }
    if (t < SCH) {
        int r = boff[b] + ts[t] - v;
        rowptr[base + t] = r;
        cursor[base + t] = r;
    }
    if (b == SCB - 1 && t == SCH - 1) rowptr[N_NODES] = boff[b] + ts[t];
}

// emeta.w = etype | rid<<3 | src<<8   (src < 65536)
__global__ void k_fill(const int* __restrict__ src, const int* __restrict__ dst,
                       const int* __restrict__ etype, const int* __restrict__ rid,
                       const void* __restrict__ att_rc, const void* __restrict__ att_rp,
                       int* __restrict__ cursor, uint4* __restrict__ emeta,
                       const int* __restrict__ flagp) {
    const int f32 = *flagp;
    int i = blockIdx.x * blockDim.x + threadIdx.x;
    int stride = gridDim.x * blockDim.x;
    for (int e = i; e < N_EDGES; e += stride) {
        int d = dst[e];
        int j = atomicAdd(&cursor[d], 1);
        float rc0 = LD(att_rc, 2 * (size_t)e, f32), rc1 = LD(att_rc, 2 * (size_t)e + 1, f32);
        float rp0 = LD(att_rp, 3 * (size_t)e, f32), rp1 = LD(att_rp, 3 * (size_t)e + 1, f32),
              rp2 = LD(att_rp, 3 * (size_t)e + 2, f32);
        uint4 m;
        m.x = pk2(rc0, rc1);
        m.y = pk2(rp0, rp1);
        m.z = pk2(rp2, 0.f);
        m.w = (unsigned)(etype[e] | (rid[e] << 3) | ((unsigned)src[e] << 8));
        emeta[j] = m;
    }
}

// ---------------- initial feature MLP --------------------------------------
__global__ void k_init(const void* __restrict__ feat,
                       const void* __restrict__ W0, const void* __restrict__ b0,
                       const void* __restrict__ W1, const void* __restrict__ b1,
                       float* __restrict__ feats, const int* __restrict__ flagp) {
    const int f32 = *flagp;
    __shared__ float sf[64 * 12];
    __shared__ float sW0[IN_DIM * 64];
    __shared__ float sb0[64], sb1[64];
    __shared__ float sh[64 * 64];
    __shared__ float sW1[64 * 64];
    int tid = threadIdx.x, n0 = blockIdx.x * 64;
    for (int i = tid; i < IN_DIM * 64; i += 256) sW0[i] = LD(W0, i, f32);
    for (int i = tid; i < 64; i += 256) { sb0[i] = LD(b0, i, f32); sb1[i] = LD(b1, i, f32); }
    for (int i = tid; i < 64 * 64; i += 256) sW1[i] = LD(W1, i, f32);
    for (int i = tid; i < 64 * IN_DIM; i += 256) {
        int n = n0 + i / IN_DIM, c = i % IN_DIM;
        sf[(i / IN_DIM) * 12 + c] = (n < N_NODES) ? LD(feat, (size_t)n * IN_DIM + c, f32) : 0.f;
    }
    __syncthreads();
    int ng = tid / 16, cg = tid % 16;
    float acc[4][4];
    #pragma unroll
    for (int i = 0; i < 4; i++)
        #pragma unroll
        for (int j = 0; j < 4; j++) acc[i][j] = sb0[cg * 4 + j];
    #pragma unroll
    for (int k = 0; k < IN_DIM; k++)
        #pragma unroll
        for (int i = 0; i < 4; i++) {
            float a = sf[(ng * 4 + i) * 12 + k];
            #pragma unroll
            for (int j = 0; j < 4; j++) acc[i][j] += a * sW0[k * 64 + cg * 4 + j];
        }
    #pragma unroll
    for (int i = 0; i < 4; i++)
        #pragma unroll
        for (int j = 0; j < 4; j++) sh[(ng * 4 + i) * 64 + cg * 4 + j] = fmaxf(acc[i][j], 0.f);
    __syncthreads();
    float o[4][4];
    #pragma unroll
    for (int i = 0; i < 4; i++)
        #pragma unroll
        for (int j = 0; j < 4; j++) o[i][j] = sb1[cg * 4 + j];
    for (int k = 0; k < 64; k++) {
        float4 bv = *(const float4*)&sW1[k * 64 + cg * 4];
        #pragma unroll
        for (int i = 0; i < 4; i++) {
            float a = sh[(ng * 4 + i) * 64 + k];
            o[i][0] += a * bv.x; o[i][1] += a * bv.y;
            o[i][2] += a * bv.z; o[i][3] += a * bv.w;
        }
    }
    #pragma unroll
    for (int i = 0; i < 4; i++) {
        int n = n0 + ng * 4 + i;
        if (n < N_NODES) {
            float* r = feats + (size_t)n * F_TOT;
            #pragma unroll
            for (int j = 0; j < 4; j++) r[IN_DIM + cg * 4 + j] = o[i][j];
        }
    }
    for (int i = tid; i < 64 * IN_DIM; i += 256) {
        int n = n0 + i / IN_DIM, c = i % IN_DIM;
        if (n < N_NODES) feats[(size_t)n * F_TOT + c] = sf[(i / IN_DIM) * 12 + c];
    }
}

// ---------------- fused edge tables ----------------------------------------
__global__ void k_tables(const void* __restrict__ etype_emb, const void* __restrict__ rid_emb,
                         const void* __restrict__ rc_W, const void* __restrict__ rc_b,
                         const void* __restrict__ rp_W, const void* __restrict__ rp_b,
                         const void* __restrict__ W_fij, const void* __restrict__ egat_bias,
                         float* __restrict__ T, const int* __restrict__ flagp) {
    const int f32 = *flagp;
    int l = blockIdx.x;
    __shared__ float S[NT_ROWS * HID];
    __shared__ float W[HID * HO];
    for (int i = threadIdx.x; i < 7 * HID; i += 256) S[i] = LD(etype_emb, i, f32);
    for (int i = threadIdx.x; i < 31 * HID; i += 256) S[7 * HID + i] = LD(rid_emb, i, f32);
    for (int i = threadIdx.x; i < 2 * HID; i += 256) S[38 * HID + i] = LD(rc_W, i, f32);
    for (int i = threadIdx.x; i < 3 * HID; i += 256) S[40 * HID + i] = LD(rp_W, i, f32);
    for (int i = threadIdx.x; i < HID; i += 256)
        S[43 * HID + i] = LD(rc_b, i, f32) + LD(rp_b, i, f32);
    for (int i = threadIdx.x; i < HID * HO; i += 256)
        W[i] = LD(W_fij, (size_t)l * HID * HO + i, f32);
    __syncthreads();
    for (int idx = threadIdx.x; idx < NT_ROWS * HO; idx += 256) {
        int r = idx / HO, c = idx % HO;
        float acc = (r == 43) ? LD(egat_bias, l * HO + c, f32) : 0.f;
        for (int k = 0; k < HID; k++) acc += S[r * HID + k] * W[k * HO + c];
        T[(size_t)l * NT_ROWS * HO + idx] = acc;
    }
}

// ---------------- node GEMMs via MFMA -> packed bf16 gather buffers --------
__global__ void __launch_bounds__(256) k_ngemm(
        const float* __restrict__ feats, int h_off,
        const unsigned short* __restrict__ pw_n, int l,
        unsigned* __restrict__ gsrc, unsigned* __restrict__ gdst) {
    __shared__ __align__(16) unsigned short Xs[64 * 72];
    __shared__ __align__(16) unsigned short Ws[384 * 72];
    int tid = threadIdx.x, n0 = blockIdx.x * 64;
    for (int i = tid; i < 64 * 64; i += 256) {
        int n = i >> 6, c = i & 63, gn = n0 + n;
        Xs[n * 72 + c] = rnebf((gn < N_NODES) ? feats[(size_t)gn * F_TOT + h_off + c] : 0.f);
    }
    const uint4* pn = (const uint4*)pw_n + (size_t)l * 3072;
    for (int i = tid; i < 3072; i += 256) {   // i = (m*128+c)*8 + kq
        int kq = i & 7, mc = i >> 3;
        *(uint4*)&Ws[mc * 72 + kq * 8] = pn[i];
    }
    __syncthreads();
    int wid = tid >> 6, lane = tid & 63;
    int row0 = wid * 16, mrow = lane & 15, quad = lane >> 4;
    bf16x8 a0 = *(const bf16x8*)&Xs[(row0 + mrow) * 72 + quad * 8];
    bf16x8 a1 = *(const bf16x8*)&Xs[(row0 + mrow) * 72 + 32 + quad * 8];
    f32x4 accA[8], accB[8];
    #pragma unroll
    for (int j = 0; j < 8; j++) { accA[j] = (f32x4){0,0,0,0}; accB[j] = (f32x4){0,0,0,0}; }
    #pragma unroll
    for (int j = 0; j < 8; j++) {
        bf16x8 b0 = *(const bf16x8*)&Ws[(0 * 128 + j * 16 + mrow) * 72 + quad * 8];
        bf16x8 b1 = *(const bf16x8*)&Ws[(0 * 128 + j * 16 + mrow) * 72 + 32 + quad * 8];
        accA[j] = __builtin_amdgcn_mfma_f32_16x16x32_bf16(a0, b0, accA[j], 0, 0, 0);
        accA[j] = __builtin_amdgcn_mfma_f32_16x16x32_bf16(a1, b1, accA[j], 0, 0, 0);
        bf16x8 c0 = *(const bf16x8*)&Ws[(2 * 128 + j * 16 + mrow) * 72 + quad * 8];
        bf16x8 c1 = *(const bf16x8*)&Ws[(2 * 128 + j * 16 + mrow) * 72 + 32 + quad * 8];
        accB[j] = __builtin_amdgcn_mfma_f32_16x16x32_bf16(a0, c0, accB[j], 0, 0, 0);
        accB[j] = __builtin_amdgcn_mfma_f32_16x16x32_bf16(a1, c1, accB[j], 0, 0, 0);
    }
    #pragma unroll
    for (int j = 0; j < 4; j++) {
        int c = j * 16 + mrow;
        #pragma unroll
        for (int r = 0; r < 4; r++) {
            int gn = n0 + row0 + quad * 4 + r;
            if (gn < N_NODES) {
                uint2 v;
                v.x = pk2(accA[j][r], accA[j + 4][r]);
                v.y = pk2(accB[j][r], accB[j + 4][r]);
                *(uint2*)&gsrc[(size_t)gn * 128 + c * 2] = v;
            }
        }
    }
    f32x4 accC[8];
    #pragma unroll
    for (int j = 0; j < 8; j++) accC[j] = (f32x4){0,0,0,0};
    #pragma unroll
    for (int j = 0; j < 8; j++) {
        bf16x8 b0 = *(const bf16x8*)&Ws[(1 * 128 + j * 16 + mrow) * 72 + quad * 8];
        bf16x8 b1 = *(const bf16x8*)&Ws[(1 * 128 + j * 16 + mrow) * 72 + 32 + quad * 8];
        accC[j] = __builtin_amdgcn_mfma_f32_16x16x32_bf16(a0, b0, accC[j], 0, 0, 0);
        accC[j] = __builtin_amdgcn_mfma_f32_16x16x32_bf16(a1, b1, accC[j], 0, 0, 0);
    }
    #pragma unroll
    for (int j = 0; j < 4; j++) {
        int c = j * 16 + mrow;
        #pragma unroll
        for (int r = 0; r < 4; r++) {
            int gn = n0 + row0 + quad * 4 + r;
            if (gn < N_NODES)
                gdst[(size_t)gn * 64 + c] = pk2(accC[j][r], accC[j + 4][r]);
        }
    }
}

// ---------------- fused edge phase (round-6 layout, no-max softmax) ---------
__global__ void __launch_bounds__(256) k_edge_fused(
        const float* __restrict__ T, const void* __restrict__ attn, int l,
        const unsigned* __restrict__ gsrc, const unsigned* __restrict__ gdst,
        const int* __restrict__ rowptr, const uint4* __restrict__ emeta,
        float* __restrict__ h_att, const int* __restrict__ flagp) {
    const int f32 = *flagp;
    __shared__ float Ts[38 * HO];
    const float* Tl = T + (size_t)l * NT_ROWS * HO;
    for (int i4 = threadIdx.x; i4 < 38 * HO / 4; i4 += 256)
        ((float4*)Ts)[i4] = ((const float4*)Tl)[i4];
    int lane = threadIdx.x & 63;
    float C0[6], C1[6];
    #pragma unroll
    for (int r = 0; r < 6; r++) {
        C0[r] = Tl[(38 + r) * HO + lane];
        C1[r] = Tl[(38 + r) * HO + 64 + lane];
    }
    float AT0 = LD(attn, l * HO + lane, f32), AT1 = LD(attn, l * HO + 64 + lane, f32);
    __syncthreads();
    int d = blockIdx.x * 4 + (threadIdx.x >> 6);
    int jb = rowptr[d], je = rowptr[d + 1];
    unsigned gd = gdst[(size_t)d * 64 + lane];
    float nj0 = plo(gd) + C0[5], nj1 = phi(gd) + C1[5];   // const row folded in
    float l0 = 0.f, a0 = 0.f, l1 = 0.f, a1 = 0.f;

    auto logits = [&](const uint4& em, const uint2& g,
                      float& e0, float& e1, float& h0, float& h1) {
        unsigned w = em.w;
        int et = (int)(w & 7u), ri = (int)((w >> 3) & 31u);
        float rc0 = plo(em.x), rc1 = phi(em.x);
        float rp0 = plo(em.y), rp1 = phi(em.y), rp2 = plo(em.z);
        float ni0 = plo(g.x), ni1 = phi(g.x);
        h0 = plo(g.y); h1 = phi(g.y);
        float x0 = ni0 + nj0 + Ts[et * HO + lane] + Ts[(7 + ri) * HO + lane]
                 + rc0 * C0[0] + rc1 * C0[1] + rp0 * C0[2] + rp1 * C0[3] + rp2 * C0[4];
        float x1 = ni1 + nj1 + Ts[et * HO + 64 + lane] + Ts[(7 + ri) * HO + 64 + lane]
                 + rc0 * C1[0] + rc1 * C1[1] + rp0 * C1[2] + rp1 * C1[3] + rp2 * C1[4];
        x0 = (x0 > 0.f) ? x0 : NEG_SLOPE * x0;
        x1 = (x1 > 0.f) ? x1 : NEG_SLOPE * x1;
        e0 = wsum(x0 * AT0);
        e1 = wsum(x1 * AT1);
    };
    auto update = [&](float e0, float e1, float h0, float h1) {
        float w0 = __expf(e0), w1 = __expf(e1);   // |e| small: no max needed
        l0 += w0; a0 = fmaf(w0, h0, a0);
        l1 += w1; a1 = fmaf(w1, h1, a1);
    };
    auto fetch = [&](int j, uint4& em, uint2& g) {
        em = emeta[j];
        g = *(const uint2*)&gsrc[(size_t)(em.w >> 8) * 128 + lane * 2];
    };

    uint4 emA = make_uint4(0,0,0,0), emB = make_uint4(0,0,0,0);
    uint2 gA = make_uint2(0,0), gB = make_uint2(0,0);
    int j = jb;
    if (j < je)     fetch(j, emA, gA);
    if (j + 1 < je) fetch(j + 1, emB, gB);
    while (j + 2 <= je) {
        float e0a, e1a, h0a, h1a, e0b, e1b, h0b, h1b;
        logits(emA, gA, e0a, e1a, h0a, h1a);   // independent wsum chains
        logits(emB, gB, e0b, e1b, h0b, h1b);
        if (j + 2 < je) fetch(j + 2, emA, gA);
        if (j + 3 < je) fetch(j + 3, emB, gB);
        update(e0a, e1a, h0a, h1a);
        update(e0b, e1b, h0b, h1b);
        j += 2;
    }
    if (j < je) {
        float e0, e1, h0, h1;
        logits(emA, gA, e0, e1, h0, h1);
        update(e0, e1, h0, h1);
    }
    h_att[(size_t)d * HO + lane]      = a0 / (l0 + 1e-9f);
    h_att[(size_t)d * HO + 64 + lane] = a1 / (l1 + 1e-9f);
}

// ---------------- node MLP + residual via MFMA ------------------------------
__global__ void __launch_bounds__(256) k_mlp(
        const float* __restrict__ h_att,
        const unsigned short* __restrict__ pw_m0, const void* __restrict__ bm0,
        const unsigned short* __restrict__ pw_m1, const void* __restrict__ bm1, int l,
        float* __restrict__ feats, int prev_off, int out_off,
        const int* __restrict__ flagp) {
    const int f32 = *flagp;
    __shared__ __align__(16) unsigned short Xs[64 * 136];
    __shared__ __align__(16) unsigned short W0T[128 * 136];
    __shared__ __align__(16) unsigned short W1T[64 * 136];
    __shared__ float sb0[HO], sb1[64];
    int tid = threadIdx.x, n0 = blockIdx.x * 64;
    for (int i = tid; i < 64 * 128; i += 256) {
        int n = i >> 7, c = i & 127, gn = n0 + n;
        Xs[n * 136 + c] = rnebf((gn < N_NODES) ? h_att[(size_t)gn * HO + c] : 0.f);
    }
    const uint4* p0 = (const uint4*)pw_m0 + (size_t)l * 2048;
    for (int i = tid; i < 2048; i += 256) {   // i = c*16 + kq
        int kq = i & 15, c = i >> 4;
        *(uint4*)&W0T[c * 136 + kq * 8] = p0[i];
    }
    const uint4* p1 = (const uint4*)pw_m1 + (size_t)l * 1024;
    for (int i = tid; i < 1024; i += 256) {
        int kq = i & 15, c = i >> 4;
        *(uint4*)&W1T[c * 136 + kq * 8] = p1[i];
    }
    for (int i = tid; i < HO; i += 256) sb0[i] = LD(bm0, l * HO + i, f32);
    for (int i = tid; i < 64; i += 256) sb1[i] = LD(bm1, l * 64 + i, f32);
    __syncthreads();
    int wid = tid >> 6, lane = tid & 63;
    int row0 = wid * 16, mrow = lane & 15, quad = lane >> 4;
    f32x4 acc[8];
    #pragma unroll
    for (int j = 0; j < 8; j++) {
        float b = sb0[j * 16 + mrow];
        acc[j] = (f32x4){b, b, b, b};
    }
    #pragma unroll
    for (int ks = 0; ks < 4; ks++) {
        bf16x8 a = *(const bf16x8*)&Xs[(row0 + mrow) * 136 + ks * 32 + quad * 8];
        #pragma unroll
        for (int j = 0; j < 8; j++) {
            bf16x8 b = *(const bf16x8*)&W0T[(j * 16 + mrow) * 136 + ks * 32 + quad * 8];
            acc[j] = __builtin_amdgcn_mfma_f32_16x16x32_bf16(a, b, acc[j], 0, 0, 0);
        }
    }
    #pragma unroll
    for (int j = 0; j < 8; j++)
        #pragma unroll
        for (int r = 0; r < 4; r++)
            Xs[(row0 + quad * 4 + r) * 136 + j * 16 + mrow] = rnebf(fmaxf(acc[j][r], 0.f));
    f32x4 o[4];
    #pragma unroll
    for (int j = 0; j < 4; j++) {
        float b = sb1[j * 16 + mrow];
        o[j] = (f32x4){b, b, b, b};
    }
    #pragma unroll
    for (int ks = 0; ks < 4; ks++) {
        bf16x8 a = *(const bf16x8*)&Xs[(row0 + mrow) * 136 + ks * 32 + quad * 8];
        #pragma unroll
        for (int j = 0; j < 4; j++) {
            bf16x8 b = *(const bf16x8*)&W1T[(j * 16 + mrow) * 136 + ks * 32 + quad * 8];
            o[j] = __builtin_amdgcn_mfma_f32_16x16x32_bf16(a, b, o[j], 0, 0, 0);
        }
    }
    #pragma unroll
    for (int j = 0; j < 4; j++) {
        int c = j * 16 + mrow;
        #pragma unroll
        for (int r = 0; r < 4; r++) {
            int gn = n0 + row0 + quad * 4 + r;
            if (gn < N_NODES) {
                float* rw = feats + (size_t)gn * F_TOT;
                rw[out_off + c] = o[j][r] + rw[prev_off + c];
            }
        }
    }
}

// ---------------- graph max pool -------------------------------------------
__global__ void k_pool(const float* __restrict__ feats, unsigned* __restrict__ gmax) {
    int g = blockIdx.x;
    int chunk = blockIdx.y;
    int t = threadIdx.x;
    const int CS = 49;
    int nb = chunk * CS;
    int ne = (nb + CS < NPG) ? nb + CS : NPG;
    float m0 = -INFINITY, m1 = -INFINITY;
    for (int n = nb; n < ne; n++) {
        const float* row = feats + (size_t)(g * NPG + n) * F_TOT;
        m0 = fmaxf(m0, row[t]);
        if (t + 256 < F_TOT) m1 = fmaxf(m1, row[t + 256]);
    }
    atomicMax(&gmax[g * F_TOT + t], fkey(m0));
    if (t + 256 < F_TOT) atomicMax(&gmax[g * F_TOT + t + 256], fkey(m1));
}

// ---------------- output write: wave per row --------------------------------
__global__ void k_out(const float* __restrict__ feats, const unsigned* __restrict__ gmax,
                      void* __restrict__ out, const int* __restrict__ flagp) {
    const int f32 = *flagp;
    int lane = threadIdx.x & 63;
    int wave = (blockIdx.x * blockDim.x + threadIdx.x) >> 6;
    int nw = (gridDim.x * blockDim.x) >> 6;
    for (int row = wave; row < B_GRAPHS * NPG; row += nw) {
        int g = row / NPG;
        const float* fr = feats + (size_t)row * F_TOT;
        const unsigned* gr = gmax + g * F_TOT;
        if (f32) {
            float* o = (float*)out + (size_t)row * OUT_C;
            for (int c = lane; c < OUT_C; c += 64)
                o[c] = (c < F_TOT) ? fr[c] : funkey(gr[c - F_TOT]);
        } else {
            __hip_bfloat16* o = (__hip_bfloat16*)out + (size_t)row * OUT_C;
            for (int c = lane; c < OUT_C; c += 64)
                o[c] = __float2bfloat16((c < F_TOT) ? fr[c] : funkey(gr[c - F_TOT]));
        }
    }
}

extern "C" void kernel_launch(void* const* d_in, const int* in_sizes, int n_in,
                              void* d_out, int out_size, void* d_ws, size_t ws_size,
                              hipStream_t stream) {
    const void* feat      = d_in[0];
    const void* att_rc    = d_in[1];
    const void* att_rp    = d_in[2];
    const void* etype_emb = d_in[3];
    const void* rid_emb   = d_in[4];
    const void* rc_W      = d_in[5];
    const void* rc_b      = d_in[6];
    const void* rp_W      = d_in[7];
    const void* rp_b      = d_in[8];
    const void* fe_W0     = d_in[9];
    const void* fe_b0     = d_in[10];
    const void* fe_W1     = d_in[11];
    const void* fe_b1     = d_in[12];
    const void* W_ni      = d_in[13];
    const void* W_nj      = d_in[14];
    const void* W_fij     = d_in[15];
    const void* W_node    = d_in[16];
    const void* attn      = d_in[17];
    const void* egat_bias = d_in[18];
    const void* Wm0       = d_in[19];
    const void* bm0       = d_in[20];
    const void* Wm1       = d_in[21];
    const void* bm1       = d_in[22];
    const int* src   = (const int*)d_in[23];
    const int* dst   = (const int*)d_in[24];
    const int* etype = (const int*)d_in[25];
    const int* rid   = (const int*)d_in[26];

    char* p = (char*)d_ws;
    auto alloc = [&](size_t bytes) {
        char* r = p;
        p += (bytes + 255) & ~(size_t)255;
        return r;
    };
    float*    feats  = (float*)alloc((size_t)N_NODES * F_TOT * 4);
    unsigned* gsrc   = (unsigned*)alloc((size_t)N_NODES * HO * 4);
    unsigned* gdst   = (unsigned*)alloc((size_t)N_NODES * 64 * 4);
    float*    h_att  = (float*)alloc((size_t)N_NODES * HO * 4);
    float*    T      = (float*)alloc((size_t)3 * NT_ROWS * HO * 4);
    unsigned* gmax   = (unsigned*)alloc((size_t)B_GRAPHS * F_TOT * 4);
    int*      flagp  = (int*)alloc(256);
    int*      rowptr = (int*)alloc((size_t)(N_NODES + 1) * 4);
    int*      cursor = (int*)alloc((size_t)N_NODES * 4);
    int*      cnt    = (int*)alloc((size_t)N_NODES * 4);
    int*      bsum   = (int*)alloc((size_t)SCB * 4);
    int*      boff   = (int*)alloc((size_t)SCB * 4);
    uint4*    emeta  = (uint4*)alloc((size_t)N_EDGES * 16);
    unsigned short* pw_n  = (unsigned short*)alloc((size_t)73728 * 2);
    unsigned short* pw_m0 = (unsigned short*)alloc((size_t)49152 * 2);
    unsigned short* pw_m1 = (unsigned short*)alloc((size_t)24576 * 2);

    k_detect<<<1, 256, 0, stream>>>(att_rc, flagp);
    hipMemsetAsync(cnt, 0, (size_t)N_NODES * 4, stream);
    hipMemsetAsync(gmax, 0, (size_t)B_GRAPHS * F_TOT * 4, stream);
    k_wprep<<<576, 256, 0, stream>>>(W_ni, W_nj, W_node, Wm0, Wm1,
                                     pw_n, pw_m0, pw_m1, flagp);
    k_count<<<512, 256, 0, stream>>>(dst, cnt);
    k_scan1<<<SCB, 256, 0, stream>>>(cnt, bsum);
    k_scan2<<<1, 256, 0, stream>>>(bsum, boff);
    k_scan3<<<SCB, 256, 0, stream>>>(cnt, boff, rowptr, cursor);
    k_fill<<<1024, 256, 0, stream>>>(src, dst, etype, rid, att_rc, att_rp,
                                     cursor, emeta, flagp);
    k_init<<<(N_NODES + 63) / 64, 256, 0, stream>>>(feat, fe_W0, fe_b0, fe_W1, fe_b1,
                                                    feats, flagp);
    k_tables<<<3, 256, 0, stream>>>(etype_emb, rid_emb, rc_W, rc_b, rp_W, rp_b,
                                    W_fij, egat_bias, T, flagp);
    for (int l = 0; l < 3; l++) {
        int h_off = IN_DIM + l * HID;
        int out_off = IN_DIM + (l + 1) * HID;
        k_ngemm<<<(N_NODES + 63) / 64, 256, 0, stream>>>(feats, h_off, pw_n, l, gsrc, gdst);
        k_edge_fused<<<N_NODES / 4, 256, 0, stream>>>(T, attn, l, gsrc, gdst,
                                                      rowptr, emeta, h_att, flagp);
        k_mlp<<<(N_NODES + 63) / 64, 256, 0, stream>>>(h_att, pw_m0, bm0, pw_m1, bm1, l,
                                                       feats, h_off, out_off, flagp);
    }
    k_pool<<<dim3(B_GRAPHS, 128), 256, 0, stream>>>(feats, gmax);
    k_out<<<2048, 256, 0, stream>>>(feats, gmax, d_out, flagp);
}